// Round 6
// baseline (542.752 us; speedup 1.0000x reference)
//
#include <hip/hip_runtime.h>
#include <hip/hip_bf16.h>
#include <math.h>

#define NB 4096
#define DC 256
#define PC 512

typedef unsigned short ushort_t;
typedef __attribute__((ext_vector_type(8))) unsigned short us8;
typedef __attribute__((ext_vector_type(8))) short s8v;       // bf16x8 for MFMA
typedef __attribute__((ext_vector_type(4))) float f32x4;

__device__ __forceinline__ float bf16_to_f(ushort_t u) {
    union { unsigned int i; float f; } c;
    c.i = ((unsigned int)u) << 16;
    return c.f;
}
__device__ __forceinline__ ushort_t f2bf(float f) {          // RNE
    union { float f; unsigned int u; } c; c.f = f;
    unsigned int r = c.u + 0x7fffu + ((c.u >> 16) & 1u);
    return (ushort_t)(r >> 16);
}

// ---------------- K0: p2 ----------------
__global__ __launch_bounds__(256) void k_prep(const float* __restrict__ proto,
                                              float* __restrict__ p2) {
    int p = blockIdx.x;       // 0..511
    int d = threadIdx.x;      // 0..255
    float v = proto[p * DC + d];
    __shared__ float red[256];
    red[d] = v * v;
    __syncthreads();
    for (int s = 128; s > 0; s >>= 1) {
        if (d < s) red[d] += red[d + s];
        __syncthreads();
    }
    if (d == 0) p2[p] = red[0];
}

// ---------------- K0a: pack proto into MFMA B-fragment layout, bf16 hi/lo ----------------
// frag[((nt*8 + k0)*64 + lane)*8 + j], n = nt*16 + (lane&15), k = k0*32 + (lane>>4)*8 + j
__global__ __launch_bounds__(256) void k_pack(const float* __restrict__ proto,
                                              ushort_t* __restrict__ pfragHi,
                                              ushort_t* __restrict__ pfragLo) {
    int idx = blockIdx.x * 256 + threadIdx.x;   // 512 blocks -> 131072
    int j  = idx & 7;
    int l  = (idx >> 3) & 63;
    int k0 = (idx >> 9) & 7;
    int nt = idx >> 12;
    int n = nt * 16 + (l & 15);
    int k = k0 * 32 + (l >> 4) * 8 + j;
    float v = proto[n * DC + k];
    ushort_t hi = f2bf(v);
    pfragHi[idx] = hi;
    pfragLo[idx] = f2bf(v - bf16_to_f(hi));
}

// ---------------- K0c: pack w3 -> B-fragments hi/lo [16 nt][5 k0][64][8], zero for k>=144 ----
__global__ __launch_bounds__(256) void k_w3p(const float* __restrict__ w3,
                                             ushort_t* __restrict__ w3fH,
                                             ushort_t* __restrict__ w3fL) {
    int idx = blockIdx.x * 256 + threadIdx.x;    // 160 blocks -> 40960
    int j = idx & 7, l = (idx >> 3) & 63;
    int q = idx >> 9;
    int k0 = q % 5, nt = q / 5;
    int d = nt * 16 + (l & 15);
    int k = k0 * 32 + (l >> 4) * 8 + j;
    float v = (k < 144) ? w3[d * 144 + k] : 0.f;
    ushort_t hi = f2bf(v);
    w3fH[idx] = hi;
    w3fL[idx] = f2bf(v - bf16_to_f(hi));
}

// ---------------- K0d: pack wd1 -> bf16 B-fragments [9 nt][8 k0][64][8] ----------------
__global__ __launch_bounds__(256) void k_wd1p(const float* __restrict__ wd1,
                                              ushort_t* __restrict__ wd1frag) {
    int idx = blockIdx.x * 256 + threadIdx.x;   // 144 blocks -> 36864
    int j  = idx & 7;
    int l  = (idx >> 3) & 63;
    int k0 = (idx >> 9) & 7;
    int nt = idx >> 12;                          // 0..8
    int n = nt * 16 + (l & 15);                  // 0..143
    int k = k0 * 32 + (l >> 4) * 8 + j;          // 0..255
    wd1frag[idx] = f2bf(wd1[k * 144 + n]);
}

// ---------------- K0e: PW = proto x wupT, stored as bf16 B-fragments for k_zup2 ----------
__global__ __launch_bounds__(256) void k_pw(
    const float* __restrict__ proto,   // [512][256]
    const float* __restrict__ wup,     // [256][6400] native cols = ch*25+pos
    ushort_t* __restrict__ PWfrag)
{
    __shared__ float As[32 * 65];
    __shared__ float Bs[32 * 64];
    int t = threadIdx.x;
    int n0 = blockIdx.x * 64;          // native col
    int m0 = blockIdx.y * 64;          // p
    int tx = t % 16, ty = t / 16;
    float acc[4][4];
#pragma unroll
    for (int i = 0; i < 4; i++)
#pragma unroll
        for (int j = 0; j < 4; j++) acc[i][j] = 0.f;

    for (int k0 = 0; k0 < 256; k0 += 32) {
        for (int i = t; i < 2048; i += 256) {
            int m = i / 32, k = i % 32;
            As[k * 65 + m] = proto[(m0 + m) * 256 + k0 + k];
        }
        for (int i = t; i < 2048; i += 256) {
            int k = i / 64, n = i % 64;
            Bs[k * 64 + n] = wup[(k0 + k) * 6400 + n0 + n];
        }
        __syncthreads();
#pragma unroll 8
        for (int k = 0; k < 32; k++) {
            float a0 = As[k * 65 + ty], a1 = As[k * 65 + ty + 16];
            float a2 = As[k * 65 + ty + 32], a3 = As[k * 65 + ty + 48];
            float b0 = Bs[k * 64 + tx], b1 = Bs[k * 64 + tx + 16];
            float b2 = Bs[k * 64 + tx + 32], b3 = Bs[k * 64 + tx + 48];
            acc[0][0] += a0 * b0; acc[0][1] += a0 * b1; acc[0][2] += a0 * b2; acc[0][3] += a0 * b3;
            acc[1][0] += a1 * b0; acc[1][1] += a1 * b1; acc[1][2] += a1 * b2; acc[1][3] += a1 * b3;
            acc[2][0] += a2 * b0; acc[2][1] += a2 * b1; acc[2][2] += a2 * b2; acc[2][3] += a2 * b3;
            acc[3][0] += a3 * b0; acc[3][1] += a3 * b1; acc[3][2] += a3 * b2; acc[3][3] += a3 * b3;
        }
        __syncthreads();
    }

#pragma unroll
    for (int i = 0; i < 4; i++) {
#pragma unroll
        for (int j = 0; j < 4; j++) {
            int p  = m0 + ty + 16 * i;
            int nn = n0 + tx + 16 * j;           // native
            int ch = nn / 25, pos = nn % 25;
            int np = pos * 256 + ch;             // n'
            int nt = np >> 4, k0p = p >> 5;
            int ll = ((p >> 3) & 3) * 16 + (np & 15);
            int jj = p & 7;
            PWfrag[(((nt * 16 + k0p) * 64) + ll) * 8 + jj] = f2bf(acc[i][j]);
        }
    }
}

// ---------------- K1: 2-image encoder + MFMA distances + softmax -> Wsm ----------------
// grid 2048 x 1024 threads. threads [0,512) -> image A, [512,1024) -> image B.
// LDS map (time-multiplexed):
//  IM region [0, 36992): imHi0@0, imLo0@9248, imHi1@18496, imLo1@27744 (each 4624 ush)
//    after conv3: mds[2][512]@0 (4096B), wred[2][16]@4096
//  H3 region [36992, 104576): per img i, base H_i = 36992 + i*33792:
//    h3hi_i@H_i (16896), h3lo_i@H_i+16896 (16896)
//    conv overlays (dead before conv3 writes h3): xb_i@H_i (3136), h1_i@H_i+3136 (6272),
//    h2_i@H_i+9408 (3136)
__global__ __launch_bounds__(1024) void k_enc_proto(
    const float* __restrict__ x,
    const float* __restrict__ w1, const float* __restrict__ b1,
    const float* __restrict__ w2, const float* __restrict__ b2,
    const float* __restrict__ g2, const float* __restrict__ bt2,
    const ushort_t* __restrict__ w3fH, const ushort_t* __restrict__ w3fL,
    const float* __restrict__ b3,
    const ushort_t* __restrict__ pfragHi, const ushort_t* __restrict__ pfragLo,
    const float* __restrict__ p2,
    float* __restrict__ md_out,    // [B][512]
    ushort_t* __restrict__ Wsm)    // [B][512] bf16 softmax weights
{
    int t = threadIdx.x;
    int img = t >> 9, tt = t & 511;
    int bimg = blockIdx.x * 2 + img;
    int w = t >> 6, l = t & 63;
    int lr = l & 15, lg = l >> 4;

    __shared__ __align__(16) unsigned char buf[104576];
    __shared__ float x2s[2][32];

    ushort_t* imHi = (ushort_t*)(buf + img * 18496);
    ushort_t* imLo = (ushort_t*)(buf + img * 18496 + 9248);
    unsigned char* Hb = buf + 36992 + img * 33792;
    ushort_t* h3hi = (ushort_t*)Hb;
    ushort_t* h3lo = (ushort_t*)(Hb + 16896);
    float* xb = (float*)Hb;
    float* h1 = (float*)(Hb + 3136);
    float* h2 = (float*)(Hb + 9408);
    float* mds  = (float*)buf;            // [2][512]
    float* wred = (float*)(buf + 4096);   // [2][16]

    const float bnr = rsqrtf(1.0f + 1e-5f);

    const float* xg = x + (size_t)bimg * 784;
    for (int i = tt; i < 784; i += 512) xb[i] = xg[i];
    if (t < 64) x2s[t >> 5][t & 31] = ((t & 31) < 25) ? 0.f : 1e30f;
    __syncthreads();

    // conv1: 1->8, k3 s2 p1, 28->14, bias+relu
    for (int o = tt; o < 8 * 196; o += 512) {
        int c = o / 196, r = o % 196, y = r / 14, xx = r % 14;
        float acc = b1[c];
        for (int sy = 0; sy < 3; sy++) {
            int iy = 2 * y - 1 + sy;
            if ((unsigned)iy >= 28u) continue;
            for (int sx = 0; sx < 3; sx++) {
                int ix = 2 * xx - 1 + sx;
                if ((unsigned)ix >= 28u) continue;
                acc += w1[c * 9 + sy * 3 + sx] * xb[iy * 28 + ix];
            }
        }
        h1[o] = fmaxf(acc, 0.f);
    }
    __syncthreads();

    // conv2: 8->16, k3 s2 p1, 14->7, bias+bn+relu
    for (int o = tt; o < 16 * 49; o += 512) {
        int c = o / 49, r = o % 49, y = r / 7, xx = r % 7;
        float acc = b2[c];
        for (int ci = 0; ci < 8; ci++) {
            for (int sy = 0; sy < 3; sy++) {
                int iy = 2 * y - 1 + sy;
                if ((unsigned)iy >= 14u) continue;
                for (int sx = 0; sx < 3; sx++) {
                    int ix = 2 * xx - 1 + sx;
                    if ((unsigned)ix >= 14u) continue;
                    acc += w2[((c * 8 + ci) * 3 + sy) * 3 + sx] * h1[ci * 196 + iy * 14 + ix];
                }
            }
        }
        float s = g2[c] * bnr;
        h2[c * 49 + r] = fmaxf(acc * s + bt2[c], 0.f);
    }
    __syncthreads();

    // im2col: patch[pos][k] (k = ci*9+s), bf16 hi/lo; zero rows 25..31 + 16-elem tail
    for (int e = tt; e < 3600; e += 512) {
        int pos = e / 144, k = e % 144;
        int ci = k / 9, s = k % 9;
        int sy = s / 3, sx = s % 3;
        int py = pos / 5, px = pos % 5;
        float v = h2[ci * 49 + (py + sy) * 7 + (px + sx)];
        ushort_t hi = f2bf(v);
        imHi[pos * 144 + k] = hi;
        imLo[pos * 144 + k] = f2bf(v - bf16_to_f(hi));
    }
    for (int e = tt; e < 1024; e += 512) {
        imHi[25 * 144 + e] = 0;
        imLo[25 * 144 + e] = 0;
    }
    __syncthreads();

    // conv3 as MFMA (per image: 8 waves x 2 nt each), bias+relu, h3 hi/lo + x2
    {
        int w8 = w & 7;
        int nt0 = 2 * w8;
        f32x4 c00 = {0,0,0,0}, c01 = {0,0,0,0}, c10 = {0,0,0,0}, c11 = {0,0,0,0};
        const s8v* WH = (const s8v*)w3fH;
        const s8v* WL = (const s8v*)w3fL;
#pragma unroll
        for (int k0 = 0; k0 < 5; k0++) {
            s8v ah0 = *(const s8v*)&imHi[lr * 144 + k0 * 32 + lg * 8];
            s8v ah1 = *(const s8v*)&imHi[(16 + lr) * 144 + k0 * 32 + lg * 8];
            s8v al0 = *(const s8v*)&imLo[lr * 144 + k0 * 32 + lg * 8];
            s8v al1 = *(const s8v*)&imLo[(16 + lr) * 144 + k0 * 32 + lg * 8];
            s8v bh0 = WH[(nt0 * 5 + k0) * 64 + l];
            s8v bl0 = WL[(nt0 * 5 + k0) * 64 + l];
            s8v bh1 = WH[((nt0 + 1) * 5 + k0) * 64 + l];
            s8v bl1 = WL[((nt0 + 1) * 5 + k0) * 64 + l];
            c00 = __builtin_amdgcn_mfma_f32_16x16x32_bf16(ah0, bh0, c00, 0, 0, 0);
            c10 = __builtin_amdgcn_mfma_f32_16x16x32_bf16(ah1, bh0, c10, 0, 0, 0);
            c00 = __builtin_amdgcn_mfma_f32_16x16x32_bf16(al0, bh0, c00, 0, 0, 0);
            c10 = __builtin_amdgcn_mfma_f32_16x16x32_bf16(al1, bh0, c10, 0, 0, 0);
            c00 = __builtin_amdgcn_mfma_f32_16x16x32_bf16(ah0, bl0, c00, 0, 0, 0);
            c10 = __builtin_amdgcn_mfma_f32_16x16x32_bf16(ah1, bl0, c10, 0, 0, 0);
            c01 = __builtin_amdgcn_mfma_f32_16x16x32_bf16(ah0, bh1, c01, 0, 0, 0);
            c11 = __builtin_amdgcn_mfma_f32_16x16x32_bf16(ah1, bh1, c11, 0, 0, 0);
            c01 = __builtin_amdgcn_mfma_f32_16x16x32_bf16(al0, bh1, c01, 0, 0, 0);
            c11 = __builtin_amdgcn_mfma_f32_16x16x32_bf16(al1, bh1, c11, 0, 0, 0);
            c01 = __builtin_amdgcn_mfma_f32_16x16x32_bf16(ah0, bl1, c01, 0, 0, 0);
            c11 = __builtin_amdgcn_mfma_f32_16x16x32_bf16(ah1, bl1, c11, 0, 0, 0);
        }
#pragma unroll
        for (int q = 0; q < 2; q++) {
            int d = (nt0 + q) * 16 + lr;
            float bb = b3[d];
            f32x4 cm0 = q ? c01 : c00;
            f32x4 cm1 = q ? c11 : c10;
#pragma unroll
            for (int mt = 0; mt < 2; mt++) {
                f32x4 cc = mt ? cm1 : cm0;
#pragma unroll
                for (int r = 0; r < 4; r++) {
                    int pos = mt * 16 + lg * 4 + r;
                    float h = fmaxf(cc[r] + bb, 0.f);
                    ushort_t hi = f2bf(h);
                    h3hi[pos * 264 + d] = hi;
                    h3lo[pos * 264 + d] = f2bf(h - bf16_to_f(hi));
                    float sq = h * h;
                    sq += __shfl_xor(sq, 1);
                    sq += __shfl_xor(sq, 2);
                    sq += __shfl_xor(sq, 4);
                    sq += __shfl_xor(sq, 8);
                    if (lr == 0) atomicAdd(&x2s[img][pos], sq);
                }
            }
        }
    }
    __syncthreads();

    // MFMA distances: wave w handles nt-pair {2w, 2w+1} for BOTH images (B reg-reuse x2)
    {
        const ushort_t* h3hi0 = (const ushort_t*)(buf + 36992);
        const ushort_t* h3lo0 = (const ushort_t*)(buf + 36992 + 16896);
        const ushort_t* h3hi1 = (const ushort_t*)(buf + 36992 + 33792);
        const ushort_t* h3lo1 = (const ushort_t*)(buf + 36992 + 33792 + 16896);
        f32x4 acc[2][2][2];   // [ntq][img][mt]
#pragma unroll
        for (int i = 0; i < 2; i++)
#pragma unroll
            for (int jm = 0; jm < 2; jm++)
#pragma unroll
                for (int mt = 0; mt < 2; mt++) acc[i][jm][mt] = (f32x4){0.f, 0.f, 0.f, 0.f};
        const s8v* BH = (const s8v*)pfragHi;
        const s8v* BL = (const s8v*)pfragLo;
        for (int k0 = 0; k0 < 8; k0++) {
            s8v ah[2][2], al[2][2];
            ah[0][0] = *(const s8v*)&h3hi0[lr * 264 + k0 * 32 + lg * 8];
            ah[0][1] = *(const s8v*)&h3hi0[(16 + lr) * 264 + k0 * 32 + lg * 8];
            al[0][0] = *(const s8v*)&h3lo0[lr * 264 + k0 * 32 + lg * 8];
            al[0][1] = *(const s8v*)&h3lo0[(16 + lr) * 264 + k0 * 32 + lg * 8];
            ah[1][0] = *(const s8v*)&h3hi1[lr * 264 + k0 * 32 + lg * 8];
            ah[1][1] = *(const s8v*)&h3hi1[(16 + lr) * 264 + k0 * 32 + lg * 8];
            al[1][0] = *(const s8v*)&h3lo1[lr * 264 + k0 * 32 + lg * 8];
            al[1][1] = *(const s8v*)&h3lo1[(16 + lr) * 264 + k0 * 32 + lg * 8];
#pragma unroll
            for (int ntq = 0; ntq < 2; ntq++) {
                int nt = w * 2 + ntq;
                s8v bh = BH[(nt * 8 + k0) * 64 + l];
                s8v bl = BL[(nt * 8 + k0) * 64 + l];
#pragma unroll
                for (int im = 0; im < 2; im++) {
                    acc[ntq][im][0] = __builtin_amdgcn_mfma_f32_16x16x32_bf16(ah[im][0], bh, acc[ntq][im][0], 0, 0, 0);
                    acc[ntq][im][1] = __builtin_amdgcn_mfma_f32_16x16x32_bf16(ah[im][1], bh, acc[ntq][im][1], 0, 0, 0);
                    acc[ntq][im][0] = __builtin_amdgcn_mfma_f32_16x16x32_bf16(al[im][0], bh, acc[ntq][im][0], 0, 0, 0);
                    acc[ntq][im][1] = __builtin_amdgcn_mfma_f32_16x16x32_bf16(al[im][1], bh, acc[ntq][im][1], 0, 0, 0);
                    acc[ntq][im][0] = __builtin_amdgcn_mfma_f32_16x16x32_bf16(ah[im][0], bl, acc[ntq][im][0], 0, 0, 0);
                    acc[ntq][im][1] = __builtin_amdgcn_mfma_f32_16x16x32_bf16(ah[im][1], bl, acc[ntq][im][1], 0, 0, 0);
                }
            }
        }
        float x2r[2][8];
#pragma unroll
        for (int im = 0; im < 2; im++)
#pragma unroll
            for (int r = 0; r < 4; r++) {
                x2r[im][r]     = x2s[im][lg * 4 + r];
                x2r[im][4 + r] = x2s[im][16 + lg * 4 + r];
            }
#pragma unroll
        for (int ntq = 0; ntq < 2; ntq++) {
            int pcol = (w * 2 + ntq) * 16 + lr;
            float p2v = p2[pcol];
#pragma unroll
            for (int im = 0; im < 2; im++) {
                float mm = 1e30f;
#pragma unroll
                for (int r = 0; r < 4; r++) {
                    float d0 = fmaxf(x2r[im][r]     - 2.f * acc[ntq][im][0][r] + p2v, 0.f);
                    float d1 = fmaxf(x2r[im][4 + r] - 2.f * acc[ntq][im][1][r] + p2v, 0.f);
                    mm = fminf(mm, fminf(d0, d1));
                }
                mm = fminf(mm, __shfl_xor(mm, 16));
                mm = fminf(mm, __shfl_xor(mm, 32));
                if (lg == 0) mds[im * 512 + pcol] = mm;
            }
        }
    }
    __syncthreads();

    // softmax over p of (-mind), per image, shfl-based
    float mind = mds[img * 512 + tt];
    md_out[(size_t)bimg * PC + tt] = mind;
    float a = -mind;
    float mx = a;
#pragma unroll
    for (int off = 1; off < 64; off <<= 1) mx = fmaxf(mx, __shfl_xor(mx, off));
    int wv = (t >> 6) & 7;
    if (l == 0) wred[img * 16 + wv] = mx;
    __syncthreads();
    float m = wred[img * 16];
#pragma unroll
    for (int i = 1; i < 8; i++) m = fmaxf(m, wred[img * 16 + i]);
    float e = expf(a - m);
    float sm = e;
#pragma unroll
    for (int off = 1; off < 64; off <<= 1) sm += __shfl_xor(sm, off);
    if (l == 0) wred[img * 16 + 8 + wv] = sm;
    __syncthreads();
    float ssum = wred[img * 16 + 8];
#pragma unroll
    for (int i = 9; i < 16; i++) ssum += wred[img * 16 + i];
    Wsm[(size_t)bimg * PC + tt] = f2bf(e / ssum);
}

// ---------------- K2: zupT = Wsm x PW (bf16 MFMA, LDS-staged B), bias+bn+relu ----------------
__global__ __launch_bounds__(512) void k_zup2(
    const ushort_t* __restrict__ Wsm,      // [4096][512]
    const ushort_t* __restrict__ PWfrag,   // [400][16][64][8]
    const float* __restrict__ bup, const float* __restrict__ gup,
    const float* __restrict__ btup,
    ushort_t* __restrict__ zupT)           // [4096][6400]
{
    __shared__ __align__(16) ushort_t Bsh[2][4096];   // 2 x 8KB
    int t = threadIdx.x;
    int w = t >> 6, l = t & 63;
    int n0 = blockIdx.x * 128;             // 50
    int m0 = blockIdx.y * 128;             // 32
    int row = m0 + w * 16 + (l & 15);
    int krow = (l >> 4) * 8;
    f32x4 acc[8];
#pragma unroll
    for (int i = 0; i < 8; i++) acc[i] = (f32x4){0.f, 0.f, 0.f, 0.f};
    const s8v* B = (const s8v*)PWfrag;
    int base = blockIdx.x * 8 * 16;        // ntb*16

    {
        s8v b0 = B[(size_t)(base + (t >> 6) * 16) * 64 + (t & 63)];
        *(s8v*)&Bsh[0][t * 8] = b0;
    }
    __syncthreads();
    for (int k0 = 0; k0 < 16; k0++) {
        int cur = k0 & 1;
        if (k0 < 15) {
            s8v bn = B[(size_t)(base + (t >> 6) * 16 + k0 + 1) * 64 + (t & 63)];
            *(s8v*)&Bsh[cur ^ 1][t * 8] = bn;
        }
        s8v a = *(const s8v*)&Wsm[(size_t)row * 512 + k0 * 32 + krow];
#pragma unroll
        for (int nt = 0; nt < 8; nt++) {
            s8v bb = *(const s8v*)&Bsh[cur][(nt * 64 + l) * 8];
            acc[nt] = __builtin_amdgcn_mfma_f32_16x16x32_bf16(a, bb, acc[nt], 0, 0, 0);
        }
        __syncthreads();
    }

    const float bnr = rsqrtf(1.0f + 1e-5f);
    int rowbase = m0 + w * 16 + (l >> 4) * 4;
#pragma unroll
    for (int nt = 0; nt < 8; nt++) {
        int n = n0 + nt * 16 + (l & 15);
        int ch = n & 255;
        float sc = gup[ch] * bnr, bb = bup[ch], bt = btup[ch];
#pragma unroll
        for (int r = 0; r < 4; r++) {
            float v = (acc[nt][r] + bb) * sc + bt;
            zupT[(size_t)(rowbase + r) * 6400 + n] = f2bf(fmaxf(v, 0.f));
        }
    }
}

// ---------------- K3: fused decoder (wd1 MFMA GEMM + gather + wd2 + wd3 + sigmoid) ----------
__global__ __launch_bounds__(256) void k_dtail(
    const ushort_t* __restrict__ zupT,     // [4096][6400] = [4096*25][256]
    const ushort_t* __restrict__ wd1frag,  // [9][8][64][8]
    const float* __restrict__ bd1, const float* __restrict__ gd1, const float* __restrict__ btd1,
    const float* __restrict__ wd2, const float* __restrict__ bd2,
    const float* __restrict__ gd2, const float* __restrict__ btd2,
    const float* __restrict__ wd3, const float* __restrict__ bd3,
    float* __restrict__ out0)
{
    int b = blockIdx.x, t = threadIdx.x;
    int w = t >> 6, l = t & 63, lr = l & 15, lg = l >> 4;
    __shared__ __align__(16) ushort_t zA[32 * 264];
    __shared__ float Ps[25][148];
    __shared__ float hd1s[16 * 49];
    __shared__ float hd2s[8 * 196];
    __shared__ float w2s[1152];
    __shared__ float w3s[72];

    const float bnr = rsqrtf(1.0f + 1e-5f);

    // stage A: 25 rows x 256 ch (rows 25-31 left garbage; their C-rows are discarded)
    for (int c = t; c < 800; c += 256) {
        int pos = c >> 5, cc = c & 31;
        *(us8*)&zA[pos * 264 + cc * 8] = *(const us8*)&zupT[(size_t)b * 6400 + c * 8];
    }
    for (int i = t; i < 1152; i += 256) w2s[i] = wd2[i];
    if (t < 72) w3s[t] = wd3[t];
    __syncthreads();

    // wd1 GEMM: Ps[25][144] = zA x wd1frag. 4 waves; wave w takes nt = w, w+4, w+8.
    {
        f32x4 acc[3][2];
#pragma unroll
        for (int i = 0; i < 3; i++)
#pragma unroll
            for (int mt = 0; mt < 2; mt++) acc[i][mt] = (f32x4){0.f, 0.f, 0.f, 0.f};
        const s8v* B = (const s8v*)wd1frag;
        for (int k0 = 0; k0 < 8; k0++) {
            s8v a0 = *(const s8v*)&zA[lr * 264 + k0 * 32 + lg * 8];
            s8v a1 = *(const s8v*)&zA[(16 + lr) * 264 + k0 * 32 + lg * 8];
#pragma unroll
            for (int i = 0; i < 3; i++) {
                int nt = w + 4 * i;
                if (nt < 9) {
                    s8v bb = B[(nt * 8 + k0) * 64 + l];
                    acc[i][0] = __builtin_amdgcn_mfma_f32_16x16x32_bf16(a0, bb, acc[i][0], 0, 0, 0);
                    acc[i][1] = __builtin_amdgcn_mfma_f32_16x16x32_bf16(a1, bb, acc[i][1], 0, 0, 0);
                }
            }
        }
#pragma unroll
        for (int i = 0; i < 3; i++) {
            int nt = w + 4 * i;
            if (nt < 9) {
                int col = nt * 16 + lr;
#pragma unroll
                for (int mt = 0; mt < 2; mt++)
#pragma unroll
                    for (int r = 0; r < 4; r++) {
                        int pos = mt * 16 + lg * 4 + r;
                        if (pos < 25) Ps[pos][col] = acc[i][mt][r];
                    }
            }
        }
    }
    __syncthreads();

    // wd1 gather + bias + bn + relu
    for (int o = t; o < 784; o += 256) {
        int co = o / 49, rr = o % 49, y = rr / 7, xx = rr % 7;
        float a = bd1[co];
        int sy0 = y - 4 > 0 ? y - 4 : 0, sy1 = y < 2 ? y : 2;
        for (int sy = sy0; sy <= sy1; sy++) {
            int iy = y - sy;
            int sx0 = xx - 4 > 0 ? xx - 4 : 0, sx1 = xx < 2 ? xx : 2;
            for (int sx = sx0; sx <= sx1; sx++) {
                int ix = xx - sx;
                a += Ps[iy * 5 + ix][co * 9 + sy * 3 + sx];
            }
        }
        float v = a * (gd1[co] * bnr) + btd1[co];
        hd1s[o] = fmaxf(v, 0.f);
    }
    __syncthreads();

    // wd2: convT 16->8, k3 s2 p1 op1, 7->14
    for (int o = t; o < 8 * 196; o += 256) {
        int co = o / 196, r = o % 196, y = r / 14, xx = r % 14;
        float a = 0.f;
        for (int sy = 0; sy < 3; sy++) {
            int yn = y + 1 - sy;
            if (yn & 1) continue;
            int iy = yn >> 1;
            if ((unsigned)iy >= 7u) continue;
            for (int sx = 0; sx < 3; sx++) {
                int xn = xx + 1 - sx;
                if (xn & 1) continue;
                int ix = xn >> 1;
                if ((unsigned)ix >= 7u) continue;
                for (int ci = 0; ci < 16; ci++)
                    a += w2s[(ci * 8 + co) * 9 + sy * 3 + sx] * hd1s[ci * 49 + iy * 7 + ix];
            }
        }
        float v = (a + bd2[co]) * (gd2[co] * bnr) + btd2[co];
        hd2s[o] = fmaxf(v, 0.f);
    }
    __syncthreads();

    // wd3: convT 8->1, k3 s2 p1 op1, 14->28, bias + sigmoid
    float* og = out0 + (size_t)b * 784;
    for (int o = t; o < 784; o += 256) {
        int y = o / 28, xx = o % 28;
        float a = bd3[0];
        for (int sy = 0; sy < 3; sy++) {
            int yn = y + 1 - sy;
            if (yn & 1) continue;
            int iy = yn >> 1;
            if ((unsigned)iy >= 14u) continue;
            for (int sx = 0; sx < 3; sx++) {
                int xn = xx + 1 - sx;
                if (xn & 1) continue;
                int ix = xn >> 1;
                if ((unsigned)ix >= 14u) continue;
                for (int ci = 0; ci < 8; ci++)
                    a += w3s[ci * 9 + sy * 3 + sx] * hd2s[ci * 196 + iy * 14 + ix];
            }
        }
        og[o] = 1.f / (1.f + expf(-a));
    }
}

extern "C" void kernel_launch(void* const* d_in, const int* in_sizes, int n_in,
                              void* d_out, int out_size, void* d_ws, size_t ws_size,
                              hipStream_t stream) {
    const float* x    = (const float*)d_in[0];
    const float* w1   = (const float*)d_in[1];
    const float* b1   = (const float*)d_in[2];
    const float* w2   = (const float*)d_in[3];
    const float* b2   = (const float*)d_in[4];
    const float* g2   = (const float*)d_in[5];
    const float* bt2  = (const float*)d_in[6];
    const float* w3   = (const float*)d_in[7];
    const float* b3   = (const float*)d_in[8];
    const float* proto= (const float*)d_in[9];
    const float* wup  = (const float*)d_in[10];
    const float* bup  = (const float*)d_in[11];
    const float* gup  = (const float*)d_in[12];
    const float* btup = (const float*)d_in[13];
    const float* wd1  = (const float*)d_in[14];
    const float* bd1  = (const float*)d_in[15];
    const float* gd1  = (const float*)d_in[16];
    const float* btd1 = (const float*)d_in[17];
    const float* wd2  = (const float*)d_in[18];
    const float* bd2  = (const float*)d_in[19];
    const float* gd2  = (const float*)d_in[20];
    const float* btd2 = (const float*)d_in[21];
    const float* wd3  = (const float*)d_in[22];
    const float* bd3  = (const float*)d_in[23];

    float* out0   = (float*)d_out;                 // [4096][784]
    float* out_md = out0 + (size_t)NB * 784;       // [4096][512]

    // ws layout
    float*    p2      = (float*)d_ws;                          // 512 f
    ushort_t* pfragHi = (ushort_t*)(p2 + 512);                 // 131072
    ushort_t* pfragLo = pfragHi + 131072;                      // 131072
    ushort_t* w3fH    = pfragLo + 131072;                      // 40960
    ushort_t* w3fL    = w3fH + 40960;                          // 40960
    ushort_t* wd1frag = w3fL + 40960;                          // 36864
    ushort_t* zupT    = wd1frag + 36864;                       // 26,214,400
    ushort_t* Wsm     = zupT + (size_t)26214400;               // 2,097,152
    ushort_t* PWfrag  = Wsm + 2097152;                         // 3,276,800

    hipLaunchKernelGGL(k_prep, dim3(PC), dim3(256), 0, stream, proto, p2);
    hipLaunchKernelGGL(k_pack, dim3(512), dim3(256), 0, stream, proto, pfragHi, pfragLo);
    hipLaunchKernelGGL(k_w3p, dim3(160), dim3(256), 0, stream, w3, w3fH, w3fL);
    hipLaunchKernelGGL(k_wd1p, dim3(144), dim3(256), 0, stream, wd1, wd1frag);
    hipLaunchKernelGGL(k_pw, dim3(100, 8), dim3(256), 0, stream, proto, wup, PWfrag);
    hipLaunchKernelGGL(k_enc_proto, dim3(NB / 2), dim3(1024), 0, stream,
                       x, w1, b1, w2, b2, g2, bt2, w3fH, w3fL, b3,
                       pfragHi, pfragLo, p2, out_md, Wsm);
    hipLaunchKernelGGL(k_zup2, dim3(50, 32), dim3(512), 0, stream,
                       Wsm, PWfrag, bup, gup, btup, zupT);
    hipLaunchKernelGGL(k_dtail, dim3(NB), dim3(256), 0, stream,
                       zupT, wd1frag, bd1, gd1, btd1, wd2, bd2, gd2, btd2, wd3, bd3, out0);
}

// Round 7
// 419.070 us; speedup vs baseline: 1.2951x; 1.2951x over previous
//
#include <hip/hip_runtime.h>
#include <hip/hip_bf16.h>
#include <math.h>

#define NB 4096
#define DC 256
#define PC 512

typedef unsigned short ushort_t;
typedef __attribute__((ext_vector_type(8))) unsigned short us8;
typedef __attribute__((ext_vector_type(8))) short s8v;       // bf16x8 for MFMA
typedef __attribute__((ext_vector_type(4))) float f32x4;

__device__ __forceinline__ float bf16_to_f(ushort_t u) {
    union { unsigned int i; float f; } c;
    c.i = ((unsigned int)u) << 16;
    return c.f;
}
__device__ __forceinline__ ushort_t f2bf(float f) {          // RNE
    union { float f; unsigned int u; } c; c.f = f;
    unsigned int r = c.u + 0x7fffu + ((c.u >> 16) & 1u);
    return (ushort_t)(r >> 16);
}

// ---------------- K0: p2 ----------------
__global__ __launch_bounds__(256) void k_prep(const float* __restrict__ proto,
                                              float* __restrict__ p2) {
    int p = blockIdx.x;
    int d = threadIdx.x;
    float v = proto[p * DC + d];
    __shared__ float red[256];
    red[d] = v * v;
    __syncthreads();
    for (int s = 128; s > 0; s >>= 1) {
        if (d < s) red[d] += red[d + s];
        __syncthreads();
    }
    if (d == 0) p2[p] = red[0];
}

// ---------------- K0a: pack proto into MFMA fragment layout, bf16 hi/lo ----------------
// frag[((nt*8 + k0)*64 + lane)*8 + j], n = nt*16 + (lane&15), k = k0*32 + (lane>>4)*8 + j
__global__ __launch_bounds__(256) void k_pack(const float* __restrict__ proto,
                                              ushort_t* __restrict__ pfragHi,
                                              ushort_t* __restrict__ pfragLo) {
    int idx = blockIdx.x * 256 + threadIdx.x;   // 512 blocks -> 131072
    int j  = idx & 7;
    int l  = (idx >> 3) & 63;
    int k0 = (idx >> 9) & 7;
    int nt = idx >> 12;
    int n = nt * 16 + (l & 15);
    int k = k0 * 32 + (l >> 4) * 8 + j;
    float v = proto[n * DC + k];
    ushort_t hi = f2bf(v);
    pfragHi[idx] = hi;
    pfragLo[idx] = f2bf(v - bf16_to_f(hi));
}

// ---------------- K0c: pack w3 -> B-fragments hi/lo [16 nt][5 k0][64][8], zero k>=144 ----
__global__ __launch_bounds__(256) void k_w3p(const float* __restrict__ w3,
                                             ushort_t* __restrict__ w3fH,
                                             ushort_t* __restrict__ w3fL) {
    int idx = blockIdx.x * 256 + threadIdx.x;    // 160 blocks -> 40960
    int j = idx & 7, l = (idx >> 3) & 63;
    int q = idx >> 9;
    int k0 = q % 5, nt = q / 5;
    int d = nt * 16 + (l & 15);
    int k = k0 * 32 + (l >> 4) * 8 + j;
    float v = (k < 144) ? w3[d * 144 + k] : 0.f;
    ushort_t hi = f2bf(v);
    w3fH[idx] = hi;
    w3fL[idx] = f2bf(v - bf16_to_f(hi));
}

// ---------------- K0d: pack wd1 -> bf16 B-fragments [9 nt][8 k0][64][8] ----------------
__global__ __launch_bounds__(256) void k_wd1p(const float* __restrict__ wd1,
                                              ushort_t* __restrict__ wd1frag) {
    int idx = blockIdx.x * 256 + threadIdx.x;   // 144 blocks -> 36864
    int j  = idx & 7;
    int l  = (idx >> 3) & 63;
    int k0 = (idx >> 9) & 7;
    int nt = idx >> 12;                          // 0..8
    int n = nt * 16 + (l & 15);
    int k = k0 * 32 + (l >> 4) * 8 + j;
    wd1frag[idx] = f2bf(wd1[k * 144 + n]);
}

// ---------------- K0e: wup -> B-fragments hi/lo [400 nt][8 k0][64][8]; n' = pos*256+ch ----
__global__ __launch_bounds__(256) void k_wupf(const float* __restrict__ wup,
                                              ushort_t* __restrict__ wupfH,
                                              ushort_t* __restrict__ wupfL) {
    int idx = blockIdx.x * 256 + threadIdx.x;    // 6400 blocks -> 1,638,400
    int j  = idx & 7;
    int l  = (idx >> 3) & 63;
    int k0 = (idx >> 9) & 7;
    int nt = idx >> 12;                          // 0..399
    int np = nt * 16 + (l & 15);                 // n' 0..6399
    int d  = k0 * 32 + (l >> 4) * 8 + j;         // 0..255
    int pos = np >> 8, ch = np & 255;
    float v = wup[d * 6400 + ch * 25 + pos];
    ushort_t hi = f2bf(v);
    wupfH[idx] = hi;
    wupfL[idx] = f2bf(v - bf16_to_f(hi));
}

// ---------------- K0f: PW = proto x wupT via MFMA (hi/lo), -> PWfrag [400][16][64][8] -----
__global__ __launch_bounds__(256) void k_pw2(
    const ushort_t* __restrict__ pfragHi, const ushort_t* __restrict__ pfragLo,
    const ushort_t* __restrict__ wupfH, const ushort_t* __restrict__ wupfL,
    ushort_t* __restrict__ PWfrag)
{
    int t = threadIdx.x;
    int w = t >> 6, l = t & 63, lr = l & 15, lg = l >> 4;
    int my = blockIdx.y;                 // p-tile 0..31
    int ntb = blockIdx.x * 16 + w * 4;   // n'-tile base (grid.x = 25)
    const s8v* AH = (const s8v*)pfragHi;
    const s8v* AL = (const s8v*)pfragLo;
    const s8v* BH = (const s8v*)wupfH;
    const s8v* BL = (const s8v*)wupfL;
    f32x4 acc[4];
#pragma unroll
    for (int q = 0; q < 4; q++) acc[q] = (f32x4){0.f, 0.f, 0.f, 0.f};
#pragma unroll
    for (int k0 = 0; k0 < 8; k0++) {
        s8v ah = AH[(my * 8 + k0) * 64 + l];
        s8v al = AL[(my * 8 + k0) * 64 + l];
#pragma unroll
        for (int q = 0; q < 4; q++) {
            s8v bh = BH[(size_t)((ntb + q) * 8 + k0) * 64 + l];
            s8v bl = BL[(size_t)((ntb + q) * 8 + k0) * 64 + l];
            acc[q] = __builtin_amdgcn_mfma_f32_16x16x32_bf16(ah, bh, acc[q], 0, 0, 0);
            acc[q] = __builtin_amdgcn_mfma_f32_16x16x32_bf16(al, bh, acc[q], 0, 0, 0);
            acc[q] = __builtin_amdgcn_mfma_f32_16x16x32_bf16(ah, bl, acc[q], 0, 0, 0);
        }
    }
#pragma unroll
    for (int q = 0; q < 4; q++) {
        int nt = ntb + q;
#pragma unroll
        for (int r = 0; r < 4; r++) {
            int p = my * 16 + lg * 4 + r;
            int k0p = p >> 5;
            int ll = ((p >> 3) & 3) * 16 + lr;
            int jj = p & 7;
            PWfrag[(((size_t)(nt * 16 + k0p) * 64) + ll) * 8 + jj] = f2bf(acc[q][r]);
        }
    }
}

// ---------------- E1: conv1+conv2+im2col+conv3(MFMA) -> h3g(hi/lo) + x2g ----------------
__global__ __launch_bounds__(512) void k_enc1(
    const float* __restrict__ x,
    const float* __restrict__ w1, const float* __restrict__ b1,
    const float* __restrict__ w2, const float* __restrict__ b2,
    const float* __restrict__ g2, const float* __restrict__ bt2,
    const ushort_t* __restrict__ w3fH, const ushort_t* __restrict__ w3fL,
    const float* __restrict__ b3,
    ushort_t* __restrict__ h3g,    // [4096][2][25][256]
    float* __restrict__ x2g)       // [4096][32]
{
    int b = blockIdx.x;
    int t = threadIdx.x;
    int w = t >> 6, l = t & 63, lr = l & 15, lg = l >> 4;

    // LDS overlays: xb@0(3136) h1@3136(6272) h2@9408(3136) ; imHi@0(9248) imLo@12544(9248)
    __shared__ __align__(16) unsigned char buf[21792];
    __shared__ float x2s[32];
    float* xb = (float*)buf;
    float* h1 = (float*)(buf + 3136);
    float* h2 = (float*)(buf + 9408);
    ushort_t* imHi = (ushort_t*)buf;
    ushort_t* imLo = (ushort_t*)(buf + 12544);

    const float bnr = rsqrtf(1.0f + 1e-5f);

    const float* xg = x + (size_t)b * 784;
    for (int i = t; i < 784; i += 512) xb[i] = xg[i];
    if (t < 32) x2s[t] = (t < 25) ? 0.f : 1e30f;
    __syncthreads();

    // conv1
    for (int o = t; o < 8 * 196; o += 512) {
        int c = o / 196, r = o % 196, y = r / 14, xx = r % 14;
        float acc = b1[c];
        for (int sy = 0; sy < 3; sy++) {
            int iy = 2 * y - 1 + sy;
            if ((unsigned)iy >= 28u) continue;
            for (int sx = 0; sx < 3; sx++) {
                int ix = 2 * xx - 1 + sx;
                if ((unsigned)ix >= 28u) continue;
                acc += w1[c * 9 + sy * 3 + sx] * xb[iy * 28 + ix];
            }
        }
        h1[o] = fmaxf(acc, 0.f);
    }
    __syncthreads();

    // conv2
    for (int o = t; o < 16 * 49; o += 512) {
        int c = o / 49, r = o % 49, y = r / 7, xx = r % 7;
        float acc = b2[c];
        for (int ci = 0; ci < 8; ci++) {
            for (int sy = 0; sy < 3; sy++) {
                int iy = 2 * y - 1 + sy;
                if ((unsigned)iy >= 14u) continue;
                for (int sx = 0; sx < 3; sx++) {
                    int ix = 2 * xx - 1 + sx;
                    if ((unsigned)ix >= 14u) continue;
                    acc += w2[((c * 8 + ci) * 3 + sy) * 3 + sx] * h1[ci * 196 + iy * 14 + ix];
                }
            }
        }
        float s = g2[c] * bnr;
        h2[c * 49 + r] = fmaxf(acc * s + bt2[c], 0.f);
    }
    __syncthreads();

    // im2col (over dead xb/h1)
    for (int e = t; e < 3600; e += 512) {
        int pos = e / 144, k = e % 144;
        int ci = k / 9, s = k % 9;
        int sy = s / 3, sx = s % 3;
        int py = pos / 5, px = pos % 5;
        float v = h2[ci * 49 + (py + sy) * 7 + (px + sx)];
        ushort_t hi = f2bf(v);
        imHi[pos * 144 + k] = hi;
        imLo[pos * 144 + k] = f2bf(v - bf16_to_f(hi));
    }
    for (int e = t; e < 1024; e += 512) {
        imHi[25 * 144 + e] = 0;
        imLo[25 * 144 + e] = 0;
    }
    __syncthreads();

    // conv3 as MFMA, bias+relu; write h3g (pos<25) + x2
    {
        int nt0 = 2 * w;
        f32x4 c00 = {0,0,0,0}, c01 = {0,0,0,0}, c10 = {0,0,0,0}, c11 = {0,0,0,0};
        const s8v* WH = (const s8v*)w3fH;
        const s8v* WL = (const s8v*)w3fL;
#pragma unroll
        for (int k0 = 0; k0 < 5; k0++) {
            s8v ah0 = *(const s8v*)&imHi[lr * 144 + k0 * 32 + lg * 8];
            s8v ah1 = *(const s8v*)&imHi[(16 + lr) * 144 + k0 * 32 + lg * 8];
            s8v al0 = *(const s8v*)&imLo[lr * 144 + k0 * 32 + lg * 8];
            s8v al1 = *(const s8v*)&imLo[(16 + lr) * 144 + k0 * 32 + lg * 8];
            s8v bh0 = WH[(nt0 * 5 + k0) * 64 + l];
            s8v bl0 = WL[(nt0 * 5 + k0) * 64 + l];
            s8v bh1 = WH[((nt0 + 1) * 5 + k0) * 64 + l];
            s8v bl1 = WL[((nt0 + 1) * 5 + k0) * 64 + l];
            c00 = __builtin_amdgcn_mfma_f32_16x16x32_bf16(ah0, bh0, c00, 0, 0, 0);
            c10 = __builtin_amdgcn_mfma_f32_16x16x32_bf16(ah1, bh0, c10, 0, 0, 0);
            c00 = __builtin_amdgcn_mfma_f32_16x16x32_bf16(al0, bh0, c00, 0, 0, 0);
            c10 = __builtin_amdgcn_mfma_f32_16x16x32_bf16(al1, bh0, c10, 0, 0, 0);
            c00 = __builtin_amdgcn_mfma_f32_16x16x32_bf16(ah0, bl0, c00, 0, 0, 0);
            c10 = __builtin_amdgcn_mfma_f32_16x16x32_bf16(ah1, bl0, c10, 0, 0, 0);
            c01 = __builtin_amdgcn_mfma_f32_16x16x32_bf16(ah0, bh1, c01, 0, 0, 0);
            c11 = __builtin_amdgcn_mfma_f32_16x16x32_bf16(ah1, bh1, c11, 0, 0, 0);
            c01 = __builtin_amdgcn_mfma_f32_16x16x32_bf16(al0, bh1, c01, 0, 0, 0);
            c11 = __builtin_amdgcn_mfma_f32_16x16x32_bf16(al1, bh1, c11, 0, 0, 0);
            c01 = __builtin_amdgcn_mfma_f32_16x16x32_bf16(ah0, bl1, c01, 0, 0, 0);
            c11 = __builtin_amdgcn_mfma_f32_16x16x32_bf16(ah1, bl1, c11, 0, 0, 0);
        }
        ushort_t* hg = h3g + (size_t)b * 12800;
#pragma unroll
        for (int q = 0; q < 2; q++) {
            int d = (nt0 + q) * 16 + lr;
            float bb = b3[d];
            f32x4 cm0 = q ? c01 : c00;
            f32x4 cm1 = q ? c11 : c10;
#pragma unroll
            for (int mt = 0; mt < 2; mt++) {
                f32x4 cc = mt ? cm1 : cm0;
#pragma unroll
                for (int r = 0; r < 4; r++) {
                    int pos = mt * 16 + lg * 4 + r;
                    if (pos < 25) {
                        float h = fmaxf(cc[r] + bb, 0.f);
                        ushort_t hi = f2bf(h);
                        hg[pos * 256 + d] = hi;
                        hg[6400 + pos * 256 + d] = f2bf(h - bf16_to_f(hi));
                        float sq = h * h;
                        sq += __shfl_xor(sq, 1);
                        sq += __shfl_xor(sq, 2);
                        sq += __shfl_xor(sq, 4);
                        sq += __shfl_xor(sq, 8);
                        if (lr == 0) atomicAdd(&x2s[pos], sq);
                    }
                }
            }
        }
    }
    __syncthreads();
    if (t < 32) x2g[(size_t)b * 32 + t] = x2s[t];
}

// ---------------- E2: MFMA distances + softmax -> md_out, Wsm (2 img/block) ----------------
__global__ __launch_bounds__(1024) void k_enc2(
    const ushort_t* __restrict__ h3g,     // [4096][2][25][256]
    const float* __restrict__ x2g,        // [4096][32]
    const ushort_t* __restrict__ pfragHi, const ushort_t* __restrict__ pfragLo,
    const float* __restrict__ p2,
    float* __restrict__ md_out,
    ushort_t* __restrict__ Wsm)
{
    int t = threadIdx.x;
    int b0 = blockIdx.x * 2;
    int w = t >> 6, l = t & 63, lr = l & 15, lg = l >> 4;

    __shared__ __align__(16) ushort_t h3s[2][2][32][264];   // 67584 B
    __shared__ float mds[2][512];
    __shared__ float x2sh[2][32];
    __shared__ float wred[2][16];

    // stage h3 (rows>=25 and pad tail zeroed)
    for (int i = t; i < 4224; i += 1024) {   // 2img*2hl*32pos*33chunks
        int c   = i % 33;
        int pos = (i / 33) % 32;
        int hl  = (i / (33 * 32)) % 2;
        int im  = i / (33 * 32 * 2);
        us8 v = {0, 0, 0, 0, 0, 0, 0, 0};
        if (pos < 25 && c < 32)
            v = *(const us8*)&h3g[(size_t)(b0 + im) * 12800 + hl * 6400 + pos * 256 + c * 8];
        *(us8*)&h3s[im][hl][pos][c * 8] = v;
    }
    if (t < 64) x2sh[t >> 5][t & 31] = x2g[(size_t)(b0 + (t >> 5)) * 32 + (t & 31)];
    __syncthreads();

    // dist MFMA: wave w handles nt-pair {2w,2w+1} for both images
    {
        const ushort_t* h3hi0 = &h3s[0][0][0][0];
        const ushort_t* h3lo0 = &h3s[0][1][0][0];
        const ushort_t* h3hi1 = &h3s[1][0][0][0];
        const ushort_t* h3lo1 = &h3s[1][1][0][0];
        f32x4 acc[2][2][2];   // [ntq][img][mt]
#pragma unroll
        for (int i = 0; i < 2; i++)
#pragma unroll
            for (int jm = 0; jm < 2; jm++)
#pragma unroll
                for (int mt = 0; mt < 2; mt++) acc[i][jm][mt] = (f32x4){0.f, 0.f, 0.f, 0.f};
        const s8v* BH = (const s8v*)pfragHi;
        const s8v* BL = (const s8v*)pfragLo;
        for (int k0 = 0; k0 < 8; k0++) {
            s8v ah[2][2], al[2][2];
            ah[0][0] = *(const s8v*)&h3hi0[lr * 264 + k0 * 32 + lg * 8];
            ah[0][1] = *(const s8v*)&h3hi0[(16 + lr) * 264 + k0 * 32 + lg * 8];
            al[0][0] = *(const s8v*)&h3lo0[lr * 264 + k0 * 32 + lg * 8];
            al[0][1] = *(const s8v*)&h3lo0[(16 + lr) * 264 + k0 * 32 + lg * 8];
            ah[1][0] = *(const s8v*)&h3hi1[lr * 264 + k0 * 32 + lg * 8];
            ah[1][1] = *(const s8v*)&h3hi1[(16 + lr) * 264 + k0 * 32 + lg * 8];
            al[1][0] = *(const s8v*)&h3lo1[lr * 264 + k0 * 32 + lg * 8];
            al[1][1] = *(const s8v*)&h3lo1[(16 + lr) * 264 + k0 * 32 + lg * 8];
#pragma unroll
            for (int ntq = 0; ntq < 2; ntq++) {
                int nt = w * 2 + ntq;
                s8v bh = BH[(nt * 8 + k0) * 64 + l];
                s8v bl = BL[(nt * 8 + k0) * 64 + l];
#pragma unroll
                for (int im = 0; im < 2; im++) {
                    acc[ntq][im][0] = __builtin_amdgcn_mfma_f32_16x16x32_bf16(ah[im][0], bh, acc[ntq][im][0], 0, 0, 0);
                    acc[ntq][im][1] = __builtin_amdgcn_mfma_f32_16x16x32_bf16(ah[im][1], bh, acc[ntq][im][1], 0, 0, 0);
                    acc[ntq][im][0] = __builtin_amdgcn_mfma_f32_16x16x32_bf16(al[im][0], bh, acc[ntq][im][0], 0, 0, 0);
                    acc[ntq][im][1] = __builtin_amdgcn_mfma_f32_16x16x32_bf16(al[im][1], bh, acc[ntq][im][1], 0, 0, 0);
                    acc[ntq][im][0] = __builtin_amdgcn_mfma_f32_16x16x32_bf16(ah[im][0], bl, acc[ntq][im][0], 0, 0, 0);
                    acc[ntq][im][1] = __builtin_amdgcn_mfma_f32_16x16x32_bf16(ah[im][1], bl, acc[ntq][im][1], 0, 0, 0);
                }
            }
        }
        float x2r[2][8];
#pragma unroll
        for (int im = 0; im < 2; im++)
#pragma unroll
            for (int r = 0; r < 4; r++) {
                x2r[im][r]     = x2sh[im][lg * 4 + r];
                x2r[im][4 + r] = x2sh[im][16 + lg * 4 + r];
            }
#pragma unroll
        for (int ntq = 0; ntq < 2; ntq++) {
            int pcol = (w * 2 + ntq) * 16 + lr;
            float p2v = p2[pcol];
#pragma unroll
            for (int im = 0; im < 2; im++) {
                float mm = 1e30f;
#pragma unroll
                for (int r = 0; r < 4; r++) {
                    float d0 = fmaxf(x2r[im][r]     - 2.f * acc[ntq][im][0][r] + p2v, 0.f);
                    float d1 = fmaxf(x2r[im][4 + r] - 2.f * acc[ntq][im][1][r] + p2v, 0.f);
                    mm = fminf(mm, fminf(d0, d1));
                }
                mm = fminf(mm, __shfl_xor(mm, 16));
                mm = fminf(mm, __shfl_xor(mm, 32));
                if (lg == 0) mds[im][pcol] = mm;
            }
        }
    }
    __syncthreads();

    // softmax, per image (waves 0-7 img0, 8-15 img1)
    int img = t >> 9, tt = t & 511;
    float mind = mds[img][tt];
    md_out[(size_t)(b0 + img) * PC + tt] = mind;
    float a = -mind;
    float mx = a;
#pragma unroll
    for (int off = 1; off < 64; off <<= 1) mx = fmaxf(mx, __shfl_xor(mx, off));
    int wv = w & 7;
    if (l == 0) wred[img][wv] = mx;
    __syncthreads();
    float m = wred[img][0];
#pragma unroll
    for (int i = 1; i < 8; i++) m = fmaxf(m, wred[img][i]);
    float e = expf(a - m);
    float sm = e;
#pragma unroll
    for (int off = 1; off < 64; off <<= 1) sm += __shfl_xor(sm, off);
    if (l == 0) wred[img][8 + wv] = sm;
    __syncthreads();
    float ssum = wred[img][8];
#pragma unroll
    for (int i = 9; i < 16; i++) ssum += wred[img][i];
    Wsm[(size_t)(b0 + img) * PC + tt] = f2bf(e / ssum);
}

// ---------------- K2: zupT = Wsm x PW (bf16 MFMA, LDS-staged B), bias+bn+relu ------------
__global__ __launch_bounds__(512) void k_zup2(
    const ushort_t* __restrict__ Wsm,      // [4096][512]
    const ushort_t* __restrict__ PWfrag,   // [400][16][64][8]
    const float* __restrict__ bup, const float* __restrict__ gup,
    const float* __restrict__ btup,
    ushort_t* __restrict__ zupT)           // [4096][6400]
{
    __shared__ __align__(16) ushort_t Bsh[2][4096];
    int t = threadIdx.x;
    int w = t >> 6, l = t & 63;
    int n0 = blockIdx.x * 128;             // 50
    int m0 = blockIdx.y * 128;             // 32
    int row = m0 + w * 16 + (l & 15);
    int krow = (l >> 4) * 8;
    f32x4 acc[8];
#pragma unroll
    for (int i = 0; i < 8; i++) acc[i] = (f32x4){0.f, 0.f, 0.f, 0.f};
    const s8v* B = (const s8v*)PWfrag;
    int base = blockIdx.x * 8 * 16;

    {
        s8v b0 = B[(size_t)(base + (t >> 6) * 16) * 64 + (t & 63)];
        *(s8v*)&Bsh[0][t * 8] = b0;
    }
    __syncthreads();
    for (int k0 = 0; k0 < 16; k0++) {
        int cur = k0 & 1;
        if (k0 < 15) {
            s8v bn = B[(size_t)(base + (t >> 6) * 16 + k0 + 1) * 64 + (t & 63)];
            *(s8v*)&Bsh[cur ^ 1][t * 8] = bn;
        }
        s8v a = *(const s8v*)&Wsm[(size_t)row * 512 + k0 * 32 + krow];
#pragma unroll
        for (int nt = 0; nt < 8; nt++) {
            s8v bb = *(const s8v*)&Bsh[cur][(nt * 64 + l) * 8];
            acc[nt] = __builtin_amdgcn_mfma_f32_16x16x32_bf16(a, bb, acc[nt], 0, 0, 0);
        }
        __syncthreads();
    }

    const float bnr = rsqrtf(1.0f + 1e-5f);
    int rowbase = m0 + w * 16 + (l >> 4) * 4;
#pragma unroll
    for (int nt = 0; nt < 8; nt++) {
        int n = n0 + nt * 16 + (l & 15);
        int ch = n & 255;
        float sc = gup[ch] * bnr, bb = bup[ch], bt = btup[ch];
#pragma unroll
        for (int r = 0; r < 4; r++) {
            float v = (acc[nt][r] + bb) * sc + bt;
            zupT[(size_t)(rowbase + r) * 6400 + n] = f2bf(fmaxf(v, 0.f));
        }
    }
}

// ---------------- K3: fused decoder, 512 thr, vectorized LDS layouts ----------------
__global__ __launch_bounds__(512) void k_dtail(
    const ushort_t* __restrict__ zupT,     // [4096][6400] = [4096*25][256]
    const ushort_t* __restrict__ wd1frag,  // [9][8][64][8]
    const float* __restrict__ bd1, const float* __restrict__ gd1, const float* __restrict__ btd1,
    const float* __restrict__ wd2, const float* __restrict__ bd2,
    const float* __restrict__ gd2, const float* __restrict__ btd2,
    const float* __restrict__ wd3, const float* __restrict__ bd3,
    float* __restrict__ out0)
{
    int b = blockIdx.x, t = threadIdx.x;
    int w = t >> 6, l = t & 63, lr = l & 15, lg = l >> 4;
    __shared__ __align__(16) unsigned char dbuf[16896];   // zA then Ps
    __shared__ float hd1s[49 * 16];        // [pos][ci]
    __shared__ float hd2s[196 * 8];        // [pos][co]
    __shared__ float w2s[8 * 9 * 16];      // [co][s][ci]
    __shared__ float w3sT[9 * 8];          // [s][ci]
    ushort_t* zA = (ushort_t*)dbuf;        // [32][264]
    float (*Ps)[148] = (float (*)[148])dbuf;

    const float bnr = rsqrtf(1.0f + 1e-5f);

    for (int c = t; c < 800; c += 512) {
        int pos = c >> 5, cc = c & 31;
        *(us8*)&zA[pos * 264 + cc * 8] = *(const us8*)&zupT[(size_t)b * 6400 + c * 8];
    }
    for (int i = t; i < 1152; i += 512) {
        int ci = i & 15, rest = i >> 4;
        int s = rest % 9, co = rest / 9;
        w2s[i] = wd2[(ci * 8 + co) * 9 + s];
    }
    if (t < 72) {
        int ci = t & 7, s = t >> 3;
        w3sT[t] = wd3[ci * 9 + s];
    }
    __syncthreads();

    // wd1 GEMM: Ps[25][144] = zA x wd1frag. 8 waves: nt=w; wave0 also nt=8.
    {
        f32x4 acc[2][2];
#pragma unroll
        for (int i = 0; i < 2; i++)
#pragma unroll
            for (int mt = 0; mt < 2; mt++) acc[i][mt] = (f32x4){0.f, 0.f, 0.f, 0.f};
        const s8v* B = (const s8v*)wd1frag;
        for (int k0 = 0; k0 < 8; k0++) {
            s8v a0 = *(const s8v*)&zA[lr * 264 + k0 * 32 + lg * 8];
            s8v a1 = *(const s8v*)&zA[(16 + lr) * 264 + k0 * 32 + lg * 8];
            s8v bb0 = B[(w * 8 + k0) * 64 + l];
            acc[0][0] = __builtin_amdgcn_mfma_f32_16x16x32_bf16(a0, bb0, acc[0][0], 0, 0, 0);
            acc[0][1] = __builtin_amdgcn_mfma_f32_16x16x32_bf16(a1, bb0, acc[0][1], 0, 0, 0);
            if (w == 0) {
                s8v bb1 = B[(8 * 8 + k0) * 64 + l];
                acc[1][0] = __builtin_amdgcn_mfma_f32_16x16x32_bf16(a0, bb1, acc[1][0], 0, 0, 0);
                acc[1][1] = __builtin_amdgcn_mfma_f32_16x16x32_bf16(a1, bb1, acc[1][1], 0, 0, 0);
            }
        }
        __syncthreads();   // all zA reads done; Ps overlays zA
#pragma unroll
        for (int i = 0; i < 2; i++) {
            int nt = i ? 8 : w;
            if (i == 0 || w == 0) {
                int col = nt * 16 + lr;
#pragma unroll
                for (int mt = 0; mt < 2; mt++)
#pragma unroll
                    for (int r = 0; r < 4; r++) {
                        int pos = mt * 16 + lg * 4 + r;
                        if (pos < 25) Ps[pos][col] = acc[i][mt][r];
                    }
            }
        }
    }
    __syncthreads();

    // gather + bias + bn + relu -> hd1s[pos][ci]
    for (int o = t; o < 784; o += 512) {
        int co = o / 49, rr = o % 49, y = rr / 7, xx = rr % 7;
        float a = bd1[co];
        int sy0 = y - 4 > 0 ? y - 4 : 0, sy1 = y < 2 ? y : 2;
        for (int sy = sy0; sy <= sy1; sy++) {
            int iy = y - sy;
            int sx0 = xx - 4 > 0 ? xx - 4 : 0, sx1 = xx < 2 ? xx : 2;
            for (int sx = sx0; sx <= sx1; sx++) {
                int ix = xx - sx;
                a += Ps[iy * 5 + ix][co * 9 + sy * 3 + sx];
            }
        }
        float v = a * (gd1[co] * bnr) + btd1[co];
        hd1s[rr * 16 + co] = fmaxf(v, 0.f);
    }
    __syncthreads();

    // wd2: convT 16->8, float4-vectorized over ci
    for (int o = t; o < 8 * 196; o += 512) {
        int co = o / 196, r = o % 196, y = r / 14, xx = r % 14;
        float4 s4 = {0.f, 0.f, 0.f, 0.f};
        for (int sy = 0; sy < 3; sy++) {
            int yn = y + 1 - sy;
            if (yn & 1) continue;
            int iy = yn >> 1;
            if ((unsigned)iy >= 7u) continue;
            for (int sx = 0; sx < 3; sx++) {
                int xn = xx + 1 - sx;
                if (xn & 1) continue;
                int ix = xn >> 1;
                if ((unsigned)ix >= 7u) continue;
                const float4* hp = (const float4*)&hd1s[(iy * 7 + ix) * 16];
                const float4* wp = (const float4*)&w2s[(co * 9 + sy * 3 + sx) * 16];
#pragma unroll
                for (int q2 = 0; q2 < 4; q2++) {
                    float4 hv = hp[q2], wv = wp[q2];
                    s4.x = fmaf(hv.x, wv.x, s4.x);
                    s4.y = fmaf(hv.y, wv.y, s4.y);
                    s4.z = fmaf(hv.z, wv.z, s4.z);
                    s4.w = fmaf(hv.w, wv.w, s4.w);
                }
            }
        }
        float a = s4.x + s4.y + s4.z + s4.w;
        float v = (a + bd2[co]) * (gd2[co] * bnr) + btd2[co];
        hd2s[r * 8 + co] = fmaxf(v, 0.f);
    }
    __syncthreads();

    // wd3 + sigmoid
    float* og = out0 + (size_t)b * 784;
    for (int o = t; o < 784; o += 512) {
        int y = o / 28, xx = o % 28;
        float4 s4 = {0.f, 0.f, 0.f, 0.f};
        for (int sy = 0; sy < 3; sy++) {
            int yn = y + 1 - sy;
            if (yn & 1) continue;
            int iy = yn >> 1;
            if ((unsigned)iy >= 14u) continue;
            for (int sx = 0; sx < 3; sx++) {
                int xn = xx + 1 - sx;
                if (xn & 1) continue;
                int ix = xn >> 1;
                if ((unsigned)ix >= 14u) continue;
                const float4* hp = (const float4*)&hd2s[(iy * 14 + ix) * 8];
                const float4* wp = (const float4*)&w3sT[(sy * 3 + sx) * 8];
#pragma unroll
                for (int q2 = 0; q2 < 2; q2++) {
                    float4 hv = hp[q2], wv = wp[q2];
                    s4.x = fmaf(hv.x, wv.x, s4.x);
                    s4.y = fmaf(hv.y, wv.y, s4.y);
                    s4.z = fmaf(hv.z, wv.z, s4.z);
                    s4.w = fmaf(hv.w, wv.w, s4.w);
                }
            }
        }
        float a = bd3[0] + s4.x + s4.y + s4.z + s4.w;
        og[o] = 1.f / (1.f + expf(-a));
    }
}

extern "C" void kernel_launch(void* const* d_in, const int* in_sizes, int n_in,
                              void* d_out, int out_size, void* d_ws, size_t ws_size,
                              hipStream_t stream) {
    const float* x    = (const float*)d_in[0];
    const float* w1   = (const float*)d_in[1];
    const float* b1   = (const float*)d_in[2];
    const float* w2   = (const float*)d_in[3];
    const float* b2   = (const float*)d_in[4];
    const float* g2   = (const float*)d_in[5];
    const float* bt2  = (const float*)d_in[6];
    const float* w3   = (const float*)d_in[7];
    const float* b3   = (const float*)d_in[8];
    const float* proto= (const float*)d_in[9];
    const float* wup  = (const float*)d_in[10];
    const float* bup  = (const float*)d_in[11];
    const float* gup  = (const float*)d_in[12];
    const float* btup = (const float*)d_in[13];
    const float* wd1  = (const float*)d_in[14];
    const float* bd1  = (const float*)d_in[15];
    const float* gd1  = (const float*)d_in[16];
    const float* btd1 = (const float*)d_in[17];
    const float* wd2  = (const float*)d_in[18];
    const float* bd2  = (const float*)d_in[19];
    const float* gd2  = (const float*)d_in[20];
    const float* btd2 = (const float*)d_in[21];
    const float* wd3  = (const float*)d_in[22];
    const float* bd3  = (const float*)d_in[23];

    float* out0   = (float*)d_out;                 // [4096][784]
    float* out_md = out0 + (size_t)NB * 784;       // [4096][512]

    // ws layout
    float*    p2      = (float*)d_ws;                          // 512 f
    float*    x2g     = p2 + 512;                              // 131072 f
    ushort_t* pfragHi = (ushort_t*)(x2g + 131072);             // 131072
    ushort_t* pfragLo = pfragHi + 131072;                      // 131072
    ushort_t* w3fH    = pfragLo + 131072;                      // 40960
    ushort_t* w3fL    = w3fH + 40960;                          // 40960
    ushort_t* wd1frag = w3fL + 40960;                          // 36864
    ushort_t* wupfH   = wd1frag + 36864;                       // 1638400
    ushort_t* wupfL   = wupfH + 1638400;                       // 1638400
    ushort_t* PWfrag  = wupfL + 1638400;                       // 3276800
    ushort_t* Wsm     = PWfrag + 3276800;                      // 2097152
    ushort_t* BIG     = Wsm + 2097152;                         // 52428800 (h3g, later zupT)
    ushort_t* h3g     = BIG;                                   // [4096][2][25][256]
    ushort_t* zupT    = BIG;                                   // [4096][6400] (aliases dead h3g)

    hipLaunchKernelGGL(k_prep, dim3(PC), dim3(256), 0, stream, proto, p2);
    hipLaunchKernelGGL(k_pack, dim3(512), dim3(256), 0, stream, proto, pfragHi, pfragLo);
    hipLaunchKernelGGL(k_w3p, dim3(160), dim3(256), 0, stream, w3, w3fH, w3fL);
    hipLaunchKernelGGL(k_wd1p, dim3(144), dim3(256), 0, stream, wd1, wd1frag);
    hipLaunchKernelGGL(k_wupf, dim3(6400), dim3(256), 0, stream, wup, wupfH, wupfL);
    hipLaunchKernelGGL(k_pw2, dim3(25, 32), dim3(256), 0, stream,
                       pfragHi, pfragLo, wupfH, wupfL, PWfrag);
    hipLaunchKernelGGL(k_enc1, dim3(NB), dim3(512), 0, stream,
                       x, w1, b1, w2, b2, g2, bt2, w3fH, w3fL, b3, h3g, x2g);
    hipLaunchKernelGGL(k_enc2, dim3(NB / 2), dim3(1024), 0, stream,
                       h3g, x2g, pfragHi, pfragLo, p2, out_md, Wsm);
    hipLaunchKernelGGL(k_zup2, dim3(50, 32), dim3(512), 0, stream,
                       Wsm, PWfrag, bup, gup, btup, zupT);
    hipLaunchKernelGGL(k_dtail, dim3(NB), dim3(512), 0, stream,
                       zupT, wd1frag, bd1, gd1, btd1, wd2, bd2, gd2, btd2, wd3, bd3, out0);
}

// Round 8
// 377.865 us; speedup vs baseline: 1.4364x; 1.1090x over previous
//
#include <hip/hip_runtime.h>
#include <hip/hip_bf16.h>
#include <math.h>

#define NB 4096
#define DC 256
#define PC 512

typedef unsigned short ushort_t;
typedef __attribute__((ext_vector_type(4))) unsigned short us4;
typedef __attribute__((ext_vector_type(8))) unsigned short us8;
typedef __attribute__((ext_vector_type(8))) short s8v;       // bf16x8 for MFMA
typedef __attribute__((ext_vector_type(4))) float f32x4;

__device__ __forceinline__ float bf16_to_f(ushort_t u) {
    union { unsigned int i; float f; } c;
    c.i = ((unsigned int)u) << 16;
    return c.f;
}
__device__ __forceinline__ ushort_t f2bf(float f) {          // RNE
    union { float f; unsigned int u; } c; c.f = f;
    unsigned int r = c.u + 0x7fffu + ((c.u >> 16) & 1u);
    return (ushort_t)(r >> 16);
}

// ---------------- K0: p2 ----------------
__global__ __launch_bounds__(256) void k_prep(const float* __restrict__ proto,
                                              float* __restrict__ p2) {
    int p = blockIdx.x;
    int d = threadIdx.x;
    float v = proto[p * DC + d];
    __shared__ float red[256];
    red[d] = v * v;
    __syncthreads();
    for (int s = 128; s > 0; s >>= 1) {
        if (d < s) red[d] += red[d + s];
        __syncthreads();
    }
    if (d == 0) p2[p] = red[0];
}

// ---------------- K0a: pack proto into MFMA fragment layout, bf16 hi/lo ----------------
__global__ __launch_bounds__(256) void k_pack(const float* __restrict__ proto,
                                              ushort_t* __restrict__ pfragHi,
                                              ushort_t* __restrict__ pfragLo) {
    int idx = blockIdx.x * 256 + threadIdx.x;   // 512 blocks -> 131072
    int j  = idx & 7;
    int l  = (idx >> 3) & 63;
    int k0 = (idx >> 9) & 7;
    int nt = idx >> 12;
    int n = nt * 16 + (l & 15);
    int k = k0 * 32 + (l >> 4) * 8 + j;
    float v = proto[n * DC + k];
    ushort_t hi = f2bf(v);
    pfragHi[idx] = hi;
    pfragLo[idx] = f2bf(v - bf16_to_f(hi));
}

// ---------------- K0c: pack w3 -> B-fragments hi/lo [16 nt][5 k0][64][8], zero k>=144 ----
__global__ __launch_bounds__(256) void k_w3p(const float* __restrict__ w3,
                                             ushort_t* __restrict__ w3fH,
                                             ushort_t* __restrict__ w3fL) {
    int idx = blockIdx.x * 256 + threadIdx.x;    // 160 blocks -> 40960
    int j = idx & 7, l = (idx >> 3) & 63;
    int q = idx >> 9;
    int k0 = q % 5, nt = q / 5;
    int d = nt * 16 + (l & 15);
    int k = k0 * 32 + (l >> 4) * 8 + j;
    float v = (k < 144) ? w3[d * 144 + k] : 0.f;
    ushort_t hi = f2bf(v);
    w3fH[idx] = hi;
    w3fL[idx] = f2bf(v - bf16_to_f(hi));
}

// ---------------- K0g: pack w2 -> B-fragments hi/lo [3 k0][64][8], zero k>=72 ----------
__global__ __launch_bounds__(256) void k_w2p(const float* __restrict__ w2,
                                             ushort_t* __restrict__ w2fH,
                                             ushort_t* __restrict__ w2fL) {
    int idx = blockIdx.x * 256 + threadIdx.x;    // 6 blocks -> 1536
    int j = idx & 7, l = (idx >> 3) & 63;
    int k0 = idx >> 9;                           // 0..2
    int ch = l & 15;
    int k = k0 * 32 + (l >> 4) * 8 + j;          // 0..95
    float v = (k < 72) ? w2[ch * 72 + k] : 0.f;
    ushort_t hi = f2bf(v);
    w2fH[idx] = hi;
    w2fL[idx] = f2bf(v - bf16_to_f(hi));
}

// ---------------- K0d: pack wd1 -> bf16 B-fragments [9 nt][8 k0][64][8] ----------------
__global__ __launch_bounds__(256) void k_wd1p(const float* __restrict__ wd1,
                                              ushort_t* __restrict__ wd1frag) {
    int idx = blockIdx.x * 256 + threadIdx.x;   // 144 blocks -> 36864
    int j  = idx & 7;
    int l  = (idx >> 3) & 63;
    int k0 = (idx >> 9) & 7;
    int nt = idx >> 12;                          // 0..8
    int n = nt * 16 + (l & 15);
    int k = k0 * 32 + (l >> 4) * 8 + j;
    wd1frag[idx] = f2bf(wd1[k * 144 + n]);
}

// ---------------- K0e: wup -> B-fragments hi/lo [400 nt][8 k0][64][8]; n' = pos*256+ch ----
__global__ __launch_bounds__(256) void k_wupf(const float* __restrict__ wup,
                                              ushort_t* __restrict__ wupfH,
                                              ushort_t* __restrict__ wupfL) {
    int idx = blockIdx.x * 256 + threadIdx.x;    // 6400 blocks -> 1,638,400
    int j  = idx & 7;
    int l  = (idx >> 3) & 63;
    int k0 = (idx >> 9) & 7;
    int nt = idx >> 12;                          // 0..399
    int np = nt * 16 + (l & 15);                 // n' 0..6399
    int d  = k0 * 32 + (l >> 4) * 8 + j;         // 0..255
    int pos = np >> 8, ch = np & 255;
    float v = wup[d * 6400 + ch * 25 + pos];
    ushort_t hi = f2bf(v);
    wupfH[idx] = hi;
    wupfL[idx] = f2bf(v - bf16_to_f(hi));
}

// ---------------- K0f: PW = proto x wupT via MFMA (hi/lo), -> PWfrag [400][16][64][8] -----
__global__ __launch_bounds__(256) void k_pw2(
    const ushort_t* __restrict__ pfragHi, const ushort_t* __restrict__ pfragLo,
    const ushort_t* __restrict__ wupfH, const ushort_t* __restrict__ wupfL,
    ushort_t* __restrict__ PWfrag)
{
    int t = threadIdx.x;
    int w = t >> 6, l = t & 63, lr = l & 15, lg = l >> 4;
    int my = blockIdx.y;                 // p-tile 0..31
    int ntb = blockIdx.x * 16 + w * 4;   // n'-tile base (grid.x = 25)
    const s8v* AH = (const s8v*)pfragHi;
    const s8v* AL = (const s8v*)pfragLo;
    const s8v* BH = (const s8v*)wupfH;
    const s8v* BL = (const s8v*)wupfL;
    f32x4 acc[4];
#pragma unroll
    for (int q = 0; q < 4; q++) acc[q] = (f32x4){0.f, 0.f, 0.f, 0.f};
#pragma unroll
    for (int k0 = 0; k0 < 8; k0++) {
        s8v ah = AH[(my * 8 + k0) * 64 + l];
        s8v al = AL[(my * 8 + k0) * 64 + l];
#pragma unroll
        for (int q = 0; q < 4; q++) {
            s8v bh = BH[(size_t)((ntb + q) * 8 + k0) * 64 + l];
            s8v bl = BL[(size_t)((ntb + q) * 8 + k0) * 64 + l];
            acc[q] = __builtin_amdgcn_mfma_f32_16x16x32_bf16(ah, bh, acc[q], 0, 0, 0);
            acc[q] = __builtin_amdgcn_mfma_f32_16x16x32_bf16(al, bh, acc[q], 0, 0, 0);
            acc[q] = __builtin_amdgcn_mfma_f32_16x16x32_bf16(ah, bl, acc[q], 0, 0, 0);
        }
    }
#pragma unroll
    for (int q = 0; q < 4; q++) {
        int nt = ntb + q;
#pragma unroll
        for (int r = 0; r < 4; r++) {
            int p = my * 16 + lg * 4 + r;
            int k0p = p >> 5;
            int ll = ((p >> 3) & 3) * 16 + lr;
            int jj = p & 7;
            PWfrag[(((size_t)(nt * 16 + k0p) * 64) + ll) * 8 + jj] = f2bf(acc[q][r]);
        }
    }
}

// ---------------- E1: conv1 + conv2(MFMA) + conv3(MFMA) -> h3gP(u32 hi|lo) + x2g ----------
__global__ __launch_bounds__(512) void k_enc1(
    const float* __restrict__ x,
    const float* __restrict__ w1, const float* __restrict__ b1,
    const ushort_t* __restrict__ w2fH, const ushort_t* __restrict__ w2fL,
    const float* __restrict__ b2,
    const float* __restrict__ g2, const float* __restrict__ bt2,
    const ushort_t* __restrict__ w3fH, const ushort_t* __restrict__ w3fL,
    const float* __restrict__ b3,
    unsigned int* __restrict__ h3gP,   // [4096][25][256] u32 (hi | lo<<16)
    float* __restrict__ x2g)           // [4096][32]
{
    int b = blockIdx.x;
    int t = threadIdx.x;
    int w = t >> 6, l = t & 63, lr = l & 15, lg = l >> 4;

    // LDS layout (time-multiplexed):
    //  xb@0(3136) h1@3136(6272) | im2Hi@9408(13312) im2Lo@22720(13312) | h2@36032(3136)
    //  conv3 im2col: imHi@0(9248) imLo@9248(9248) (overlays dead xb/h1/im2Hi-head)
    __shared__ __align__(16) unsigned char buf[39168];
    __shared__ float x2s[32];
    float* xb = (float*)buf;
    float* h1 = (float*)(buf + 3136);
    ushort_t* im2Hi = (ushort_t*)(buf + 9408);
    ushort_t* im2Lo = (ushort_t*)(buf + 22720);
    float* h2 = (float*)(buf + 36032);
    ushort_t* imHi = (ushort_t*)buf;
    ushort_t* imLo = (ushort_t*)(buf + 9248 + 9248 - 9248 + 9248);  // = buf + 9248
    imLo = (ushort_t*)(buf + 9248);

    const float bnr = rsqrtf(1.0f + 1e-5f);

    const float* xg = x + (size_t)b * 784;
    for (int i = t; i < 784; i += 512) xb[i] = xg[i];
    if (t < 32) x2s[t] = (t < 25) ? 0.f : 1e30f;
    __syncthreads();

    // conv1: 1->8, k3 s2 p1, 28->14, bias+relu (scalar)
    for (int o = t; o < 8 * 196; o += 512) {
        int c = o / 196, r = o % 196, y = r / 14, xx = r % 14;
        float acc = b1[c];
        for (int sy = 0; sy < 3; sy++) {
            int iy = 2 * y - 1 + sy;
            if ((unsigned)iy >= 28u) continue;
            for (int sx = 0; sx < 3; sx++) {
                int ix = 2 * xx - 1 + sx;
                if ((unsigned)ix >= 28u) continue;
                acc += w1[c * 9 + sy * 3 + sx] * xb[iy * 28 + ix];
            }
        }
        h1[o] = fmaxf(acc, 0.f);
    }
    __syncthreads();

    // im2col for conv2: im2[pos(64)][k(104 stride, 96 used)] hi/lo, zero invalid
    for (int e = t; e < 64 * 104; e += 512) {
        int pos = e / 104, k = e % 104;
        float v = 0.f;
        if (pos < 49 && k < 72) {
            int ci = k / 9, s = k % 9;
            int sy = s / 3, sx = s % 3;
            int y = pos / 7, xx = pos % 7;
            int iy = 2 * y - 1 + sy, ix = 2 * xx - 1 + sx;
            if ((unsigned)iy < 14u && (unsigned)ix < 14u)
                v = h1[ci * 196 + iy * 14 + ix];
        }
        ushort_t hi = f2bf(v);
        im2Hi[e] = hi;
        im2Lo[e] = f2bf(v - bf16_to_f(hi));
    }
    __syncthreads();

    // conv2 as MFMA: C[64 pos][16 ch] = im2 x w2frag (hi/lo 3-term). Waves 0-3, m-tile=w.
    if (w < 4) {
        f32x4 cc = {0, 0, 0, 0};
        const s8v* WH = (const s8v*)w2fH;
        const s8v* WL = (const s8v*)w2fL;
#pragma unroll
        for (int k0 = 0; k0 < 3; k0++) {
            s8v a0 = *(const s8v*)&im2Hi[(w * 16 + lr) * 104 + k0 * 32 + lg * 8];
            s8v a1 = *(const s8v*)&im2Lo[(w * 16 + lr) * 104 + k0 * 32 + lg * 8];
            s8v bh = WH[k0 * 64 + l];
            s8v bl = WL[k0 * 64 + l];
            cc = __builtin_amdgcn_mfma_f32_16x16x32_bf16(a0, bh, cc, 0, 0, 0);
            cc = __builtin_amdgcn_mfma_f32_16x16x32_bf16(a1, bh, cc, 0, 0, 0);
            cc = __builtin_amdgcn_mfma_f32_16x16x32_bf16(a0, bl, cc, 0, 0, 0);
        }
        int ch = lr;
        float s = g2[ch] * bnr, bb = b2[ch], bt = bt2[ch];
#pragma unroll
        for (int r = 0; r < 4; r++) {
            int pos = w * 16 + lg * 4 + r;
            if (pos < 49)
                h2[ch * 49 + pos] = fmaxf((cc[r] + bb) * s + bt, 0.f);
        }
    }
    __syncthreads();

    // im2col for conv3 (overlays dead xb/h1/im2 head)
    for (int e = t; e < 3600; e += 512) {
        int pos = e / 144, k = e % 144;
        int ci = k / 9, s = k % 9;
        int sy = s / 3, sx = s % 3;
        int py = pos / 5, px = pos % 5;
        float v = h2[ci * 49 + (py + sy) * 7 + (px + sx)];
        ushort_t hi = f2bf(v);
        imHi[pos * 144 + k] = hi;
        imLo[pos * 144 + k] = f2bf(v - bf16_to_f(hi));
    }
    for (int e = t; e < 1024; e += 512) {
        imHi[25 * 144 + e] = 0;
        imLo[25 * 144 + e] = 0;
    }
    __syncthreads();

    // conv3 as MFMA, bias+relu; packed u32 store + x2
    {
        int nt0 = 2 * w;
        f32x4 c00 = {0,0,0,0}, c01 = {0,0,0,0}, c10 = {0,0,0,0}, c11 = {0,0,0,0};
        const s8v* WH = (const s8v*)w3fH;
        const s8v* WL = (const s8v*)w3fL;
#pragma unroll
        for (int k0 = 0; k0 < 5; k0++) {
            s8v ah0 = *(const s8v*)&imHi[lr * 144 + k0 * 32 + lg * 8];
            s8v ah1 = *(const s8v*)&imHi[(16 + lr) * 144 + k0 * 32 + lg * 8];
            s8v al0 = *(const s8v*)&imLo[lr * 144 + k0 * 32 + lg * 8];
            s8v al1 = *(const s8v*)&imLo[(16 + lr) * 144 + k0 * 32 + lg * 8];
            s8v bh0 = WH[(nt0 * 5 + k0) * 64 + l];
            s8v bl0 = WL[(nt0 * 5 + k0) * 64 + l];
            s8v bh1 = WH[((nt0 + 1) * 5 + k0) * 64 + l];
            s8v bl1 = WL[((nt0 + 1) * 5 + k0) * 64 + l];
            c00 = __builtin_amdgcn_mfma_f32_16x16x32_bf16(ah0, bh0, c00, 0, 0, 0);
            c10 = __builtin_amdgcn_mfma_f32_16x16x32_bf16(ah1, bh0, c10, 0, 0, 0);
            c00 = __builtin_amdgcn_mfma_f32_16x16x32_bf16(al0, bh0, c00, 0, 0, 0);
            c10 = __builtin_amdgcn_mfma_f32_16x16x32_bf16(al1, bh0, c10, 0, 0, 0);
            c00 = __builtin_amdgcn_mfma_f32_16x16x32_bf16(ah0, bl0, c00, 0, 0, 0);
            c10 = __builtin_amdgcn_mfma_f32_16x16x32_bf16(ah1, bl0, c10, 0, 0, 0);
            c01 = __builtin_amdgcn_mfma_f32_16x16x32_bf16(ah0, bh1, c01, 0, 0, 0);
            c11 = __builtin_amdgcn_mfma_f32_16x16x32_bf16(ah1, bh1, c11, 0, 0, 0);
            c01 = __builtin_amdgcn_mfma_f32_16x16x32_bf16(al0, bh1, c01, 0, 0, 0);
            c11 = __builtin_amdgcn_mfma_f32_16x16x32_bf16(al1, bh1, c11, 0, 0, 0);
            c01 = __builtin_amdgcn_mfma_f32_16x16x32_bf16(ah0, bl1, c01, 0, 0, 0);
            c11 = __builtin_amdgcn_mfma_f32_16x16x32_bf16(ah1, bl1, c11, 0, 0, 0);
        }
        unsigned int* hg = h3gP + (size_t)b * 6400;
#pragma unroll
        for (int q = 0; q < 2; q++) {
            int d = (nt0 + q) * 16 + lr;
            float bb = b3[d];
            f32x4 cm0 = q ? c01 : c00;
            f32x4 cm1 = q ? c11 : c10;
#pragma unroll
            for (int mt = 0; mt < 2; mt++) {
                f32x4 cv = mt ? cm1 : cm0;
#pragma unroll
                for (int r = 0; r < 4; r++) {
                    int pos = mt * 16 + lg * 4 + r;
                    if (pos < 25) {
                        float h = fmaxf(cv[r] + bb, 0.f);
                        ushort_t hi = f2bf(h);
                        ushort_t lo = f2bf(h - bf16_to_f(hi));
                        hg[pos * 256 + d] = (unsigned int)hi | ((unsigned int)lo << 16);
                        float sq = h * h;
                        sq += __shfl_xor(sq, 1);
                        sq += __shfl_xor(sq, 2);
                        sq += __shfl_xor(sq, 4);
                        sq += __shfl_xor(sq, 8);
                        if (lr == 0) atomicAdd(&x2s[pos], sq);
                    }
                }
            }
        }
    }
    __syncthreads();
    if (t < 32) x2g[(size_t)b * 32 + t] = x2s[t];
}

// ---------------- E2: MFMA distances + softmax -> md_out, Wsm (2 img/block) ----------------
__global__ __launch_bounds__(1024) void k_enc2(
    const unsigned int* __restrict__ h3gP,   // [4096][25][256] u32
    const float* __restrict__ x2g,           // [4096][32]
    const ushort_t* __restrict__ pfragHi, const ushort_t* __restrict__ pfragLo,
    const float* __restrict__ p2,
    float* __restrict__ md_out,
    ushort_t* __restrict__ Wsm)
{
    int t = threadIdx.x;
    int b0 = blockIdx.x * 2;
    int w = t >> 6, l = t & 63, lr = l & 15, lg = l >> 4;

    __shared__ __align__(16) ushort_t h3s[2][2][32][264];   // 67584 B
    __shared__ float mds[2][512];
    __shared__ float x2sh[2][32];
    __shared__ float wred[2][16];

    // stage h3 with hi/lo unpack (rows >= 25 zeroed)
    for (int i = t; i < 4096; i += 1024) {   // 2img * 32pos * 64 chunks-of-4d
        int im = i >> 11, pos = (i >> 6) & 31, c4 = i & 63;
        us4 hi = {0, 0, 0, 0}, lo = {0, 0, 0, 0};
        if (pos < 25) {
            uint4 v = *(const uint4*)&h3gP[(size_t)(b0 + im) * 6400 + pos * 256 + c4 * 4];
            hi = (us4){(ushort_t)v.x, (ushort_t)v.y, (ushort_t)v.z, (ushort_t)v.w};
            lo = (us4){(ushort_t)(v.x >> 16), (ushort_t)(v.y >> 16),
                       (ushort_t)(v.z >> 16), (ushort_t)(v.w >> 16)};
        }
        *(us4*)&h3s[im][0][pos][c4 * 4] = hi;
        *(us4*)&h3s[im][1][pos][c4 * 4] = lo;
    }
    if (t < 64) x2sh[t >> 5][t & 31] = x2g[(size_t)(b0 + (t >> 5)) * 32 + (t & 31)];
    __syncthreads();

    // dist MFMA: wave w handles nt-pair {2w,2w+1} for both images
    {
        const ushort_t* h3hi0 = &h3s[0][0][0][0];
        const ushort_t* h3lo0 = &h3s[0][1][0][0];
        const ushort_t* h3hi1 = &h3s[1][0][0][0];
        const ushort_t* h3lo1 = &h3s[1][1][0][0];
        f32x4 acc[2][2][2];   // [ntq][img][mt]
#pragma unroll
        for (int i = 0; i < 2; i++)
#pragma unroll
            for (int jm = 0; jm < 2; jm++)
#pragma unroll
                for (int mt = 0; mt < 2; mt++) acc[i][jm][mt] = (f32x4){0.f, 0.f, 0.f, 0.f};
        const s8v* BH = (const s8v*)pfragHi;
        const s8v* BL = (const s8v*)pfragLo;
        for (int k0 = 0; k0 < 8; k0++) {
            s8v ah[2][2], al[2][2];
            ah[0][0] = *(const s8v*)&h3hi0[lr * 264 + k0 * 32 + lg * 8];
            ah[0][1] = *(const s8v*)&h3hi0[(16 + lr) * 264 + k0 * 32 + lg * 8];
            al[0][0] = *(const s8v*)&h3lo0[lr * 264 + k0 * 32 + lg * 8];
            al[0][1] = *(const s8v*)&h3lo0[(16 + lr) * 264 + k0 * 32 + lg * 8];
            ah[1][0] = *(const s8v*)&h3hi1[lr * 264 + k0 * 32 + lg * 8];
            ah[1][1] = *(const s8v*)&h3hi1[(16 + lr) * 264 + k0 * 32 + lg * 8];
            al[1][0] = *(const s8v*)&h3lo1[lr * 264 + k0 * 32 + lg * 8];
            al[1][1] = *(const s8v*)&h3lo1[(16 + lr) * 264 + k0 * 32 + lg * 8];
#pragma unroll
            for (int ntq = 0; ntq < 2; ntq++) {
                int nt = w * 2 + ntq;
                s8v bh = BH[(nt * 8 + k0) * 64 + l];
                s8v bl = BL[(nt * 8 + k0) * 64 + l];
#pragma unroll
                for (int im = 0; im < 2; im++) {
                    acc[ntq][im][0] = __builtin_amdgcn_mfma_f32_16x16x32_bf16(ah[im][0], bh, acc[ntq][im][0], 0, 0, 0);
                    acc[ntq][im][1] = __builtin_amdgcn_mfma_f32_16x16x32_bf16(ah[im][1], bh, acc[ntq][im][1], 0, 0, 0);
                    acc[ntq][im][0] = __builtin_amdgcn_mfma_f32_16x16x32_bf16(al[im][0], bh, acc[ntq][im][0], 0, 0, 0);
                    acc[ntq][im][1] = __builtin_amdgcn_mfma_f32_16x16x32_bf16(al[im][1], bh, acc[ntq][im][1], 0, 0, 0);
                    acc[ntq][im][0] = __builtin_amdgcn_mfma_f32_16x16x32_bf16(ah[im][0], bl, acc[ntq][im][0], 0, 0, 0);
                    acc[ntq][im][1] = __builtin_amdgcn_mfma_f32_16x16x32_bf16(ah[im][1], bl, acc[ntq][im][1], 0, 0, 0);
                }
            }
        }
        float x2r[2][8];
#pragma unroll
        for (int im = 0; im < 2; im++)
#pragma unroll
            for (int r = 0; r < 4; r++) {
                x2r[im][r]     = x2sh[im][lg * 4 + r];
                x2r[im][4 + r] = x2sh[im][16 + lg * 4 + r];
            }
#pragma unroll
        for (int ntq = 0; ntq < 2; ntq++) {
            int pcol = (w * 2 + ntq) * 16 + lr;
            float p2v = p2[pcol];
#pragma unroll
            for (int im = 0; im < 2; im++) {
                float mm = 1e30f;
#pragma unroll
                for (int r = 0; r < 4; r++) {
                    float d0 = fmaxf(x2r[im][r]     - 2.f * acc[ntq][im][0][r] + p2v, 0.f);
                    float d1 = fmaxf(x2r[im][4 + r] - 2.f * acc[ntq][im][1][r] + p2v, 0.f);
                    mm = fminf(mm, fminf(d0, d1));
                }
                mm = fminf(mm, __shfl_xor(mm, 16));
                mm = fminf(mm, __shfl_xor(mm, 32));
                if (lg == 0) mds[im][pcol] = mm;
            }
        }
    }
    __syncthreads();

    // softmax, per image (waves 0-7 img0, 8-15 img1)
    int img = t >> 9, tt = t & 511;
    float mind = mds[img][tt];
    md_out[(size_t)(b0 + img) * PC + tt] = mind;
    float a = -mind;
    float mx = a;
#pragma unroll
    for (int off = 1; off < 64; off <<= 1) mx = fmaxf(mx, __shfl_xor(mx, off));
    int wv = w & 7;
    if (l == 0) wred[img][wv] = mx;
    __syncthreads();
    float m = wred[img][0];
#pragma unroll
    for (int i = 1; i < 8; i++) m = fmaxf(m, wred[img][i]);
    float e = expf(a - m);
    float sm = e;
#pragma unroll
    for (int off = 1; off < 64; off <<= 1) sm += __shfl_xor(sm, off);
    if (l == 0) wred[img][8 + wv] = sm;
    __syncthreads();
    float ssum = wred[img][8];
#pragma unroll
    for (int i = 9; i < 16; i++) ssum += wred[img][i];
    Wsm[(size_t)(b0 + img) * PC + tt] = f2bf(e / ssum);
}

// ---------------- K2: zupT = Wsm x PW (bf16 MFMA, LDS-staged B), bias+bn+relu ------------
__global__ __launch_bounds__(512) void k_zup2(
    const ushort_t* __restrict__ Wsm,      // [4096][512]
    const ushort_t* __restrict__ PWfrag,   // [400][16][64][8]
    const float* __restrict__ bup, const float* __restrict__ gup,
    const float* __restrict__ btup,
    ushort_t* __restrict__ zupT)           // [4096][6400]
{
    __shared__ __align__(16) ushort_t Bsh[2][4096];
    int t = threadIdx.x;
    int w = t >> 6, l = t & 63;
    int n0 = blockIdx.x * 128;             // 50
    int m0 = blockIdx.y * 128;             // 32
    int row = m0 + w * 16 + (l & 15);
    int krow = (l >> 4) * 8;
    f32x4 acc[8];
#pragma unroll
    for (int i = 0; i < 8; i++) acc[i] = (f32x4){0.f, 0.f, 0.f, 0.f};
    const s8v* B = (const s8v*)PWfrag;
    int base = blockIdx.x * 8 * 16;

    {
        s8v b0 = B[(size_t)(base + (t >> 6) * 16) * 64 + (t & 63)];
        *(s8v*)&Bsh[0][t * 8] = b0;
    }
    __syncthreads();
    for (int k0 = 0; k0 < 16; k0++) {
        int cur = k0 & 1;
        if (k0 < 15) {
            s8v bn = B[(size_t)(base + (t >> 6) * 16 + k0 + 1) * 64 + (t & 63)];
            *(s8v*)&Bsh[cur ^ 1][t * 8] = bn;
        }
        s8v a = *(const s8v*)&Wsm[(size_t)row * 512 + k0 * 32 + krow];
#pragma unroll
        for (int nt = 0; nt < 8; nt++) {
            s8v bb = *(const s8v*)&Bsh[cur][(nt * 64 + l) * 8];
            acc[nt] = __builtin_amdgcn_mfma_f32_16x16x32_bf16(a, bb, acc[nt], 0, 0, 0);
        }
        __syncthreads();
    }

    const float bnr = rsqrtf(1.0f + 1e-5f);
    int rowbase = m0 + w * 16 + (l >> 4) * 4;
#pragma unroll
    for (int nt = 0; nt < 8; nt++) {
        int n = n0 + nt * 16 + (l & 15);
        int ch = n & 255;
        float sc = gup[ch] * bnr, bb = bup[ch], bt = btup[ch];
#pragma unroll
        for (int r = 0; r < 4; r++) {
            float v = (acc[nt][r] + bb) * sc + bt;
            zupT[(size_t)(rowbase + r) * 6400 + n] = f2bf(fmaxf(v, 0.f));
        }
    }
}

// ---------------- K3: fused decoder, 2 images/block (512 thr) ----------------
__global__ __launch_bounds__(512) void k_dtail(
    const ushort_t* __restrict__ zupT,     // [4096][6400]
    const ushort_t* __restrict__ wd1frag,  // [9][8][64][8]
    const float* __restrict__ bd1, const float* __restrict__ gd1, const float* __restrict__ btd1,
    const float* __restrict__ wd2, const float* __restrict__ bd2,
    const float* __restrict__ gd2, const float* __restrict__ btd2,
    const float* __restrict__ wd3, const float* __restrict__ bd3,
    float* __restrict__ out0)
{
    int b0 = blockIdx.x * 2, t = threadIdx.x;
    int w = t >> 6, l = t & 63, lr = l & 15, lg = l >> 4;
    int g = w >> 2, wv = w & 3, tg = t & 255;      // image group, wave-in-group
    __shared__ __align__(16) unsigned char dbuf[33792];   // zA[2] then Ps[2]
    __shared__ float hd1s[2][49 * 16];     // [pos][ci]
    __shared__ float hd2s[2][196 * 8];     // [pos][co]
    __shared__ float w2s[8 * 9 * 16];      // [co][s][ci]
    __shared__ float w3sT[9 * 8];          // [s][ci]
    ushort_t* zAb = (ushort_t*)dbuf;       // img i at ushort offset i*8448, [32][264]
    float* Psb = (float*)dbuf;             // img i at float offset i*4224, [25][148]

    const float bnr = rsqrtf(1.0f + 1e-5f);

    for (int c = t; c < 1600; c += 512) {
        int im = c / 800, cc = c % 800;
        *(us8*)&zAb[im * 8448 + (cc >> 5) * 264 + (cc & 31) * 8] =
            *(const us8*)&zupT[(size_t)(b0 + im) * 6400 + cc * 8];
    }
    for (int i = t; i < 1152; i += 512) {
        int ci = i & 15, rest = i >> 4;
        int s = rest % 9, co = rest / 9;
        w2s[i] = wd2[(ci * 8 + co) * 9 + s];
    }
    if (t < 72) {
        int ci = t & 7, s = t >> 3;
        w3sT[t] = wd3[ci * 9 + s];
    }
    __syncthreads();

    // wd1 GEMM per image: Ps[25][144] = zA x wd1frag. 4 waves/img; wv -> nt {wv, wv+4, wv+8}
    {
        f32x4 acc[3][2];
#pragma unroll
        for (int i = 0; i < 3; i++)
#pragma unroll
            for (int mt = 0; mt < 2; mt++) acc[i][mt] = (f32x4){0.f, 0.f, 0.f, 0.f};
        const s8v* B = (const s8v*)wd1frag;
        for (int k0 = 0; k0 < 8; k0++) {
            s8v a0 = *(const s8v*)&zAb[g * 8448 + lr * 264 + k0 * 32 + lg * 8];
            s8v a1 = *(const s8v*)&zAb[g * 8448 + (16 + lr) * 264 + k0 * 32 + lg * 8];
#pragma unroll
            for (int i = 0; i < 3; i++) {
                int nt = wv + 4 * i;
                if (nt < 9) {
                    s8v bb = B[(nt * 8 + k0) * 64 + l];
                    acc[i][0] = __builtin_amdgcn_mfma_f32_16x16x32_bf16(a0, bb, acc[i][0], 0, 0, 0);
                    acc[i][1] = __builtin_amdgcn_mfma_f32_16x16x32_bf16(a1, bb, acc[i][1], 0, 0, 0);
                }
            }
        }
        __syncthreads();   // all zA reads done; Ps overlays zA
#pragma unroll
        for (int i = 0; i < 3; i++) {
            int nt = wv + 4 * i;
            if (nt < 9) {
                int col = nt * 16 + lr;
#pragma unroll
                for (int mt = 0; mt < 2; mt++)
#pragma unroll
                    for (int r = 0; r < 4; r++) {
                        int pos = mt * 16 + lg * 4 + r;
                        if (pos < 25) Psb[g * 4224 + pos * 148 + col] = acc[i][mt][r];
                    }
            }
        }
    }
    __syncthreads();

    // gather + bias + bn + relu -> hd1s[g][pos][ci]
    for (int o = tg; o < 784; o += 256) {
        int co = o / 49, rr = o % 49, y = rr / 7, xx = rr % 7;
        float a = bd1[co];
        int sy0 = y - 4 > 0 ? y - 4 : 0, sy1 = y < 2 ? y : 2;
        for (int sy = sy0; sy <= sy1; sy++) {
            int iy = y - sy;
            int sx0 = xx - 4 > 0 ? xx - 4 : 0, sx1 = xx < 2 ? xx : 2;
            for (int sx = sx0; sx <= sx1; sx++) {
                int ix = xx - sx;
                a += Psb[g * 4224 + (iy * 5 + ix) * 148 + co * 9 + sy * 3 + sx];
            }
        }
        float v = a * (gd1[co] * bnr) + btd1[co];
        hd1s[g][rr * 16 + co] = fmaxf(v, 0.f);
    }
    __syncthreads();

    // wd2: convT 16->8, float4-vectorized over ci
    for (int o = tg; o < 8 * 196; o += 256) {
        int co = o / 196, r = o % 196, y = r / 14, xx = r % 14;
        float4 s4 = {0.f, 0.f, 0.f, 0.f};
        for (int sy = 0; sy < 3; sy++) {
            int yn = y + 1 - sy;
            if (yn & 1) continue;
            int iy = yn >> 1;
            if ((unsigned)iy >= 7u) continue;
            for (int sx = 0; sx < 3; sx++) {
                int xn = xx + 1 - sx;
                if (xn & 1) continue;
                int ix = xn >> 1;
                if ((unsigned)ix >= 7u) continue;
                const float4* hp = (const float4*)&hd1s[g][(iy * 7 + ix) * 16];
                const float4* wp = (const float4*)&w2s[(co * 9 + sy * 3 + sx) * 16];
#pragma unroll
                for (int q2 = 0; q2 < 4; q2++) {
                    float4 hv = hp[q2], wv4 = wp[q2];
                    s4.x = fmaf(hv.x, wv4.x, s4.x);
                    s4.y = fmaf(hv.y, wv4.y, s4.y);
                    s4.z = fmaf(hv.z, wv4.z, s4.z);
                    s4.w = fmaf(hv.w, wv4.w, s4.w);
                }
            }
        }
        float a = s4.x + s4.y + s4.z + s4.w;
        float v = (a + bd2[co]) * (gd2[co] * bnr) + btd2[co];
        hd2s[g][r * 8 + co] = fmaxf(v, 0.f);
    }
    __syncthreads();

    // wd3 + sigmoid
    float* og = out0 + (size_t)(b0 + g) * 784;
    for (int o = tg; o < 784; o += 256) {
        int y = o / 28, xx = o % 28;
        float4 s4 = {0.f, 0.f, 0.f, 0.f};
        for (int sy = 0; sy < 3; sy++) {
            int yn = y + 1 - sy;
            if (yn & 1) continue;
            int iy = yn >> 1;
            if ((unsigned)iy >= 14u) continue;
            for (int sx = 0; sx < 3; sx++) {
                int xn = xx + 1 - sx;
                if (xn & 1) continue;
                int ix = xn >> 1;
                if ((unsigned)ix >= 14u) continue;
                const float4* hp = (const float4*)&hd2s[g][(iy * 14 + ix) * 8];
                const float4* wp = (const float4*)&w3sT[(sy * 3 + sx) * 8];
#pragma unroll
                for (int q2 = 0; q2 < 2; q2++) {
                    float4 hv = hp[q2], wv4 = wp[q2];
                    s4.x = fmaf(hv.x, wv4.x, s4.x);
                    s4.y = fmaf(hv.y, wv4.y, s4.y);
                    s4.z = fmaf(hv.z, wv4.z, s4.z);
                    s4.w = fmaf(hv.w, wv4.w, s4.w);
                }
            }
        }
        float a = bd3[0] + s4.x + s4.y + s4.z + s4.w;
        og[o] = 1.f / (1.f + expf(-a));
    }
}

extern "C" void kernel_launch(void* const* d_in, const int* in_sizes, int n_in,
                              void* d_out, int out_size, void* d_ws, size_t ws_size,
                              hipStream_t stream) {
    const float* x    = (const float*)d_in[0];
    const float* w1   = (const float*)d_in[1];
    const float* b1   = (const float*)d_in[2];
    const float* w2   = (const float*)d_in[3];
    const float* b2   = (const float*)d_in[4];
    const float* g2   = (const float*)d_in[5];
    const float* bt2  = (const float*)d_in[6];
    const float* w3   = (const float*)d_in[7];
    const float* b3   = (const float*)d_in[8];
    const float* proto= (const float*)d_in[9];
    const float* wup  = (const float*)d_in[10];
    const float* bup  = (const float*)d_in[11];
    const float* gup  = (const float*)d_in[12];
    const float* btup = (const float*)d_in[13];
    const float* wd1  = (const float*)d_in[14];
    const float* bd1  = (const float*)d_in[15];
    const float* gd1  = (const float*)d_in[16];
    const float* btd1 = (const float*)d_in[17];
    const float* wd2  = (const float*)d_in[18];
    const float* bd2  = (const float*)d_in[19];
    const float* gd2  = (const float*)d_in[20];
    const float* btd2 = (const float*)d_in[21];
    const float* wd3  = (const float*)d_in[22];
    const float* bd3  = (const float*)d_in[23];

    float* out0   = (float*)d_out;                 // [4096][784]
    float* out_md = out0 + (size_t)NB * 784;       // [4096][512]

    // ws layout
    float*    p2      = (float*)d_ws;                          // 512 f
    float*    x2g     = p2 + 512;                              // 131072 f
    ushort_t* pfragHi = (ushort_t*)(x2g + 131072);             // 131072
    ushort_t* pfragLo = pfragHi + 131072;                      // 131072
    ushort_t* w3fH    = pfragLo + 131072;                      // 40960
    ushort_t* w3fL    = w3fH + 40960;                          // 40960
    ushort_t* w2fH    = w3fL + 40960;                          // 1536
    ushort_t* w2fL    = w2fH + 1536;                           // 1536
    ushort_t* wd1frag = w2fL + 1536;                           // 36864
    ushort_t* wupfH   = wd1frag + 36864;                       // 1638400
    ushort_t* wupfL   = wupfH + 1638400;                       // 1638400
    ushort_t* PWfrag  = wupfL + 1638400;                       // 3276800
    ushort_t* Wsm     = PWfrag + 3276800;                      // 2097152
    ushort_t* BIG     = Wsm + 2097152;                         // 104.8 MB region
    unsigned int* h3gP = (unsigned int*)BIG;                   // [4096][25][256] u32
    ushort_t* zupT    = BIG;                                   // [4096][6400] (aliases dead h3gP)

    hipLaunchKernelGGL(k_prep, dim3(PC), dim3(256), 0, stream, proto, p2);
    hipLaunchKernelGGL(k_pack, dim3(512), dim3(256), 0, stream, proto, pfragHi, pfragLo);
    hipLaunchKernelGGL(k_w3p, dim3(160), dim3(256), 0, stream, w3, w3fH, w3fL);
    hipLaunchKernelGGL(k_w2p, dim3(6), dim3(256), 0, stream, w2, w2fH, w2fL);
    hipLaunchKernelGGL(k_wd1p, dim3(144), dim3(256), 0, stream, wd1, wd1frag);
    hipLaunchKernelGGL(k_wupf, dim3(6400), dim3(256), 0, stream, wup, wupfH, wupfL);
    hipLaunchKernelGGL(k_pw2, dim3(25, 32), dim3(256), 0, stream,
                       pfragHi, pfragLo, wupfH, wupfL, PWfrag);
    hipLaunchKernelGGL(k_enc1, dim3(NB), dim3(512), 0, stream,
                       x, w1, b1, w2fH, w2fL, b2, g2, bt2, w3fH, w3fL, b3, h3gP, x2g);
    hipLaunchKernelGGL(k_enc2, dim3(NB / 2), dim3(1024), 0, stream,
                       h3gP, x2g, pfragHi, pfragLo, p2, out_md, Wsm);
    hipLaunchKernelGGL(k_zup2, dim3(50, 32), dim3(512), 0, stream,
                       Wsm, PWfrag, bup, gup, btup, zupT);
    hipLaunchKernelGGL(k_dtail, dim3(NB / 2), dim3(512), 0, stream,
                       zupT, wd1frag, bd1, gd1, btd1, wd2, bd2, gd2, btd2, wd3, bd3, out0);
}